// Round 15
// baseline (302.597 us; speedup 1.0000x reference)
//
#include <hip/hip_runtime.h>

#define HIDDEN 768
#define NQ 64
#define WINSZ 512
#define MSEQ 8192
#define BATCH 4
#define LI 77
#define MMHID 1024
#define LN_EPS 1e-5f
#define SCALE_QK 0.03608439182435161f  // 1/sqrt(768)

typedef __attribute__((ext_vector_type(8))) short short8v;
typedef __attribute__((ext_vector_type(4))) float f32x4;
typedef __attribute__((ext_vector_type(8))) unsigned short u16x8;

#define AS1 __attribute__((address_space(1)))
#define AS3 __attribute__((address_space(3)))

__device__ inline unsigned short f2bf(float f) {
    unsigned u = __float_as_uint(f);
    u += 0x7fffu + ((u >> 16) & 1u);
    return (unsigned short)(u >> 16);
}
__device__ inline float bf2f(unsigned short h) {
    return __uint_as_float(((unsigned)h) << 16);
}

// ---------------- block reduce (256 threads, 4 waves) ----------------
__device__ inline void block_reduce2_256(float& s1, float& s2, float* sm) {
    #pragma unroll
    for (int o = 32; o; o >>= 1) { s1 += __shfl_down(s1, o); s2 += __shfl_down(s2, o); }
    int lane = threadIdx.x & 63, w = threadIdx.x >> 6;
    __syncthreads();
    if (lane == 0) { sm[w] = s1; sm[4 + w] = s2; }
    __syncthreads();
    s1 = sm[0] + sm[1] + sm[2] + sm[3];
    s2 = sm[4] + sm[5] + sm[6] + sm[7];
}

// ---- q2 f32 (pre-LN) -> LN -> q2bf bf16 (4x128x768) with g*SCALE folded; qgsum per row ----
__global__ __launch_bounds__(256) void cvt_q_kernel(const float* __restrict__ q2,
                                                    const float* __restrict__ g,
                                                    const float* __restrict__ bb,
                                                    unsigned short* __restrict__ q2bf,
                                                    float* __restrict__ qgsum) {
    int blk = blockIdx.x;               // b*128 + r
    int b = blk >> 7, r = blk & 127;
    int t = threadIdx.x;
    __shared__ float sm[8];
    unsigned short* orow = q2bf + (size_t)blk * HIDDEN;
    if (r >= 64) {
        orow[t] = 0; orow[t + 256] = 0; orow[t + 512] = 0;
        return;
    }
    const float* qrow = q2 + ((size_t)(b * 64 + r)) * HIDDEN;
    float y0 = qrow[t], y1 = qrow[t + 256], y2 = qrow[t + 512];
    float s = y0 + y1 + y2, s2 = y0 * y0 + y1 * y1 + y2 * y2;
    block_reduce2_256(s, s2, sm);
    float mu = s * (1.f / 768.f);
    float var = s2 * (1.f / 768.f) - mu * mu;
    float inv = rsqrtf(var + LN_EPS);
    float qw0 = (y0 - mu) * inv * g[t]       + bb[t];
    float qw1 = (y1 - mu) * inv * g[t + 256] + bb[t + 256];
    float qw2 = (y2 - mu) * inv * g[t + 512] + bb[t + 512];
    float v0 = qw0 * g[t]       * SCALE_QK;
    float v1 = qw1 * g[t + 256] * SCALE_QK;
    float v2 = qw2 * g[t + 512] * SCALE_QK;
    orow[t] = f2bf(v0); orow[t + 256] = f2bf(v1); orow[t + 512] = f2bf(v2);
    float qs = v0 + v1 + v2, dummy = 0.f;
    block_reduce2_256(qs, dummy, sm);
    if (t == 0) qgsum[b * 64 + r] = qs;
}

// ---------------- prep kernel: 5 weight transposes + instf cvt (z=5) + x cvt (z=6,7 grid-stride) ----------------
struct PrepJobs {
    const float* W[5];
    unsigned short* Wt[5];
    int D[5];
    int C[5];
    const float* inst_in;
    unsigned short* inst_out;
    int n8_valid;
    int n8_total;
    const float* x_in;
    unsigned short* x_out;
    int n8x;
};
__global__ __launch_bounds__(256) void prep_kernel(PrepJobs tw) {
    int z = blockIdx.z;
    if (z >= 6) {
        int per_slice = (int)(gridDim.x * gridDim.y);
        int flat = blockIdx.y * gridDim.x + blockIdx.x;
        int i0 = ((z - 6) * per_slice + flat) * 256 + threadIdx.x;
        int stride = 2 * per_slice * 256;
        for (int i = i0; i < tw.n8x; i += stride) {
            const float4* p = (const float4*)(tw.x_in + (size_t)i * 8);
            float4 a = p[0], b = p[1];
            u16x8 o;
            o[0] = f2bf(a.x); o[1] = f2bf(a.y); o[2] = f2bf(a.z); o[3] = f2bf(a.w);
            o[4] = f2bf(b.x); o[5] = f2bf(b.y); o[6] = f2bf(b.z); o[7] = f2bf(b.w);
            *(u16x8*)(tw.x_out + (size_t)i * 8) = o;
        }
        return;
    }
    if (z == 5) {
        int flat = blockIdx.y * gridDim.x + blockIdx.x;
        int i = flat * 256 + threadIdx.x;
        if (i >= tw.n8_total) return;
        u16x8 o = {};
        if (i < tw.n8_valid) {
            const float4* p = (const float4*)(tw.inst_in + (size_t)i * 8);
            float4 a = p[0], b = p[1];
            o[0] = f2bf(a.x); o[1] = f2bf(a.y); o[2] = f2bf(a.z); o[3] = f2bf(a.w);
            o[4] = f2bf(b.x); o[5] = f2bf(b.y); o[6] = f2bf(b.z); o[7] = f2bf(b.w);
        }
        *(u16x8*)(tw.inst_out + (size_t)i * 8) = o;
        return;
    }
    int C = tw.C[z], D = tw.D[z];
    int n0 = blockIdx.x * 32, k0 = blockIdx.y * 32;
    if (n0 >= C || k0 >= D) return;
    const float* W = tw.W[z];
    unsigned short* Wt = tw.Wt[z];
    __shared__ float tile[32][33];
    int tx = threadIdx.x & 31, ty = (threadIdx.x >> 5);  // 32x8
    #pragma unroll
    for (int i = 0; i < 32; i += 8)
        tile[ty + i][tx] = W[(size_t)(k0 + ty + i) * C + n0 + tx];
    __syncthreads();
    #pragma unroll
    for (int i = 0; i < 32; i += 8)
        Wt[(size_t)(n0 + ty + i) * D + k0 + tx] = f2bf(tile[tx][ty + i]);
}

#define GM 32768
#define GN 1536
#define GK 1024

// ---------------- big GEMM: 256x256 tile, 8 waves, double-buffered 128KB LDS (R12 schedule) ----------------
// R15: atomic-free stat partials. 4 wn-waves own disjoint 64-col slices of the same
// rows -> per-wave slot rowpart[wn][256], plain ds_write, one barrier, 256-thread sum.
__global__ __launch_bounds__(512, 2) void gemm_kv256_kernel(const unsigned short* __restrict__ A,
                                                            const unsigned short* __restrict__ Bt,
                                                            const float* __restrict__ bias,
                                                            unsigned short* __restrict__ C,
                                                            float2* __restrict__ stat_s) {
    extern __shared__ char smem[];
    unsigned short* sA = (unsigned short*)smem;            // [2][256*64]
    unsigned short* sB = (unsigned short*)(smem + 65536);  // [2][256*64]

    int nwg = gridDim.x;                                   // 768
    int bid = blockIdx.x;
    int wg = bid;
    if ((nwg & 7) == 0) { int cpx = nwg >> 3; wg = (bid & 7) * cpx + (bid >> 3); }
    int bm = wg / (GN / 256), bn = wg % (GN / 256);
    int row0 = bm * 256, col0 = bn * 256;

    int tid = threadIdx.x;
    int lane = tid & 63, wid = tid >> 6;
    int wm = wid >> 2, wn = wid & 3;                       // 2M x 4N

    f32x4 acc[8][4] = {};

    int rS[4], cS[4];
    #pragma unroll
    for (int i = 0; i < 4; i++) {
        int ch = wid * 4 + i;
        int r = ch * 8 + (lane >> 3);
        rS[i] = r;
        cS[i] = ((lane & 7) ^ (r & 7)) << 3;
    }

    auto STAGE = [&](int k0, int pbuf) {
        unsigned short* dA = sA + pbuf * 16384;
        unsigned short* dB = sB + pbuf * 16384;
        #pragma unroll
        for (int i = 0; i < 4; i++) {
            int ch = wid * 4 + i;
            const unsigned short* ga = A + (size_t)(row0 + rS[i]) * GK + k0 + cS[i];
            __builtin_amdgcn_global_load_lds((const AS1 unsigned int*)ga,
                                             (AS3 unsigned int*)&dA[ch * 512], 16, 0, 0);
            const unsigned short* gb = Bt + (size_t)(col0 + rS[i]) * GK + k0 + cS[i];
            __builtin_amdgcn_global_load_lds((const AS1 unsigned int*)gb,
                                             (AS3 unsigned int*)&dB[ch * 512], 16, 0, 0);
        }
    };

    STAGE(0, 0);
    __syncthreads();

    for (int kt = 0; kt < GK / 64; kt++) {
        int cur = kt & 1;
        if (kt < GK / 64 - 1) STAGE((kt + 1) * 64, cur ^ 1);

        const char* lA = (const char*)(sA + cur * 16384);
        const char* lB = (const char*)(sB + cur * 16384);

        short8v bfr[4][2];
        #pragma unroll
        for (int n = 0; n < 4; n++)
            #pragma unroll
            for (int kk = 0; kk < 2; kk++) {
                int r = wn * 64 + n * 16 + (lane & 15);
                int ko = (kk * 32 + ((lane >> 4) << 3)) * 2;
                bfr[n][kk] = *(const short8v*)(lB + r * 128 + (ko ^ ((r & 7) << 4)));
            }
        #pragma unroll
        for (int p = 0; p < 4; p++) {
            short8v afr[2][2];
            #pragma unroll
            for (int mf = 0; mf < 2; mf++)
                #pragma unroll
                for (int kk = 0; kk < 2; kk++) {
                    int r = wm * 128 + (p * 2 + mf) * 16 + (lane & 15);
                    int ko = (kk * 32 + ((lane >> 4) << 3)) * 2;
                    afr[mf][kk] = *(const short8v*)(lA + r * 128 + (ko ^ ((r & 7) << 4)));
                }
            __builtin_amdgcn_s_setprio(1);
            #pragma unroll
            for (int mf = 0; mf < 2; mf++)
                #pragma unroll
                for (int n = 0; n < 4; n++)
                    #pragma unroll
                    for (int kk = 0; kk < 2; kk++)
                        acc[p * 2 + mf][n] = __builtin_amdgcn_mfma_f32_16x16x32_bf16(
                            afr[mf][kk], bfr[n][kk], acc[p * 2 + mf][n], 0, 0, 0);
            __builtin_amdgcn_s_setprio(0);
        }
        __syncthreads();
    }

    // ---- epilogue: bias + bf16 store + per-row {sum, sumsq} partials (atomic-free) ----
    float2* rowpart = (float2*)smem;   // [4][256] = 8 KB; LDS free after final barrier

    int crow = (lane >> 4) * 4;
    int ccol = lane & 15;
    int half = (col0 >= 768) ? 1 : 0;
    int tilei = (col0 - half * 768) >> 8;   // 0..2
    #pragma unroll
    for (int m = 0; m < 8; m++) {
        float rs[4] = {}, rq[4] = {};
        #pragma unroll
        for (int n = 0; n < 4; n++) {
            int gc = col0 + wn * 64 + n * 16 + ccol;
            float bv = bias[gc];
            #pragma unroll
            for (int j = 0; j < 4; j++) {
                int gr = row0 + wm * 128 + m * 16 + crow + j;
                float v = acc[m][n][j] + bv;
                C[(size_t)gr * GN + gc] = f2bf(v);
                rs[j] += v; rq[j] += v * v;
            }
        }
        #pragma unroll
        for (int j = 0; j < 4; j++) {
            float s_ = rs[j], q_ = rq[j];
            #pragma unroll
            for (int o = 8; o; o >>= 1) { s_ += __shfl_xor(s_, o); q_ += __shfl_xor(q_, o); }
            if (ccol == 0) {
                int lr = wm * 128 + m * 16 + crow + j;   // local row 0..255, unique per (wn, lr)
                rowpart[wn * 256 + lr] = make_float2(s_, q_);
            }
        }
    }
    __syncthreads();
    if (tid < 256) {
        float2 a0 = rowpart[tid], a1 = rowpart[256 + tid];
        float2 a2 = rowpart[512 + tid], a3 = rowpart[768 + tid];
        int gr = row0 + tid;
        stat_s[((size_t)gr * 2 + half) * 3 + tilei] =
            make_float2(a0.x + a1.x + a2.x + a3.x, a0.y + a1.y + a2.y + a3.y);
    }
}

// ---------------- finalize stats: sum 3 col-tile partials -> {mu*inv, inv} ----------------
__global__ __launch_bounds__(256) void stats_fin_kernel(const float2* __restrict__ part,
                                                        float2* __restrict__ stats, int n) {
    int i = blockIdx.x * 256 + threadIdx.x;
    if (i >= n) return;
    float2 a0 = part[(size_t)i * 3], a1 = part[(size_t)i * 3 + 1], a2 = part[(size_t)i * 3 + 2];
    float sx = a0.x + a1.x + a2.x;
    float sq = a0.y + a1.y + a2.y;
    float mu = sx * (1.f / 768.f);
    float var = sq * (1.f / 768.f) - mu * mu;
    float inv = rsqrtf(var + LN_EPS);
    stats[i] = make_float2(mu * inv, inv);
}

// ---------------- fallback: 128x128 GEMM (R8-verified, no stats) ----------------
__global__ __launch_bounds__(256) void gemm_kv128_kernel(const unsigned short* __restrict__ A,
                                                         const unsigned short* __restrict__ Bt,
                                                         const float* __restrict__ bias,
                                                         unsigned short* __restrict__ C) {
    __shared__ unsigned short sA[128 * 64];
    __shared__ unsigned short sB[128 * 64];

    int nwg = gridDim.x;
    int bid = blockIdx.x;
    int wg = bid;
    if ((nwg & 7) == 0) { int cpx = nwg >> 3; wg = (bid & 7) * cpx + (bid >> 3); }
    int bm = wg / (GN / 128), bn = wg % (GN / 128);
    int row0 = bm * 128, col0 = bn * 128;

    int tid = threadIdx.x;
    int lane = tid & 63, wid = tid >> 6;
    int wr = wid >> 1, wc = wid & 1;

    f32x4 acc[4][4] = {};

    int rS[4], cS[4];
    #pragma unroll
    for (int i = 0; i < 4; i++) {
        int ch = wid * 4 + i;
        int r = ch * 8 + (lane >> 3);
        rS[i] = r;
        cS[i] = ((lane & 7) ^ (r & 7)) << 3;
    }

    for (int k0 = 0; k0 < GK; k0 += 64) {
        #pragma unroll
        for (int i = 0; i < 4; i++) {
            int ch = wid * 4 + i;
            const unsigned short* ga = A + (size_t)(row0 + rS[i]) * GK + k0 + cS[i];
            __builtin_amdgcn_global_load_lds((const AS1 unsigned int*)ga,
                                             (AS3 unsigned int*)&sA[ch * 512], 16, 0, 0);
            const unsigned short* gb = Bt + (size_t)(col0 + rS[i]) * GK + k0 + cS[i];
            __builtin_amdgcn_global_load_lds((const AS1 unsigned int*)gb,
                                             (AS3 unsigned int*)&sB[ch * 512], 16, 0, 0);
        }
        __syncthreads();

        #pragma unroll
        for (int kk = 0; kk < 64; kk += 32) {
            int ko = (kk + ((lane >> 4) << 3)) * 2;
            short8v af[4], bf[4];
            #pragma unroll
            for (int m = 0; m < 4; m++) {
                int r = wr * 64 + m * 16 + (lane & 15);
                int addr = r * 128 + (ko ^ ((r & 7) << 4));
                af[m] = *(const short8v*)((const char*)sA + addr);
            }
            #pragma unroll
            for (int n = 0; n < 4; n++) {
                int r = wc * 64 + n * 16 + (lane & 15);
                int addr = r * 128 + (ko ^ ((r & 7) << 4));
                bf[n] = *(const short8v*)((const char*)sB + addr);
            }
            #pragma unroll
            for (int m = 0; m < 4; m++)
                #pragma unroll
                for (int n = 0; n < 4; n++)
                    acc[m][n] = __builtin_amdgcn_mfma_f32_16x16x32_bf16(af[m], bf[n], acc[m][n], 0, 0, 0);
        }
        __syncthreads();
    }

    int crow = (lane >> 4) * 4;
    int ccol = lane & 15;
    #pragma unroll
    for (int m = 0; m < 4; m++) {
        #pragma unroll
        for (int n = 0; n < 4; n++) {
            int gc = col0 + wc * 64 + n * 16 + ccol;
            float bv = bias[gc];
            #pragma unroll
            for (int j = 0; j < 4; j++) {
                int gr = row0 + wr * 64 + m * 16 + crow + j;
                C[(size_t)gr * GN + gc] = f2bf(acc[m][n][j] + bv);
            }
        }
    }
}

// ---------------- per-row-half LN stats from raw bf16 kv (fallback path only) ----------------
__global__ __launch_bounds__(256) void stats_kernel(const unsigned short* __restrict__ kv,
                                                    float2* __restrict__ stats) {
    int rh = blockIdx.x;
    const unsigned short* p = kv + (size_t)rh * 768;
    int t = threadIdx.x;
    float x0 = bf2f(p[t]), x1 = bf2f(p[t + 256]), x2 = bf2f(p[t + 512]);
    float s = x0 + x1 + x2, s2 = x0 * x0 + x1 * x1 + x2 * x2;
    __shared__ float sm[8];
    block_reduce2_256(s, s2, sm);
    if (t == 0) {
        float mu = s * (1.f / 768.f);
        float var = s2 * (1.f / 768.f) - mu * mu;
        float inv = rsqrtf(var + LN_EPS);
        stats[rh] = make_float2(mu * inv, inv);
    }
}

// ---------------- generic small MFMA GEMM: A(Mp x TK)bf16 @ Bt(N x TK)^T + bias ----------------
template <int TK, bool OUT_BF16>
__global__ __launch_bounds__(256) void gemm_tile_kernel(const unsigned short* __restrict__ A,
                                                        const unsigned short* __restrict__ Bt,
                                                        const float* __restrict__ bias,
                                                        void* __restrict__ Cout, int N) {
    __shared__ unsigned short sA[128 * 64];
    __shared__ unsigned short sB[128 * 64];

    int row0 = blockIdx.x * 128, col0 = blockIdx.y * 128;
    int tid = threadIdx.x;
    int lane = tid & 63, wid = tid >> 6;
    int wr = wid >> 1, wc = wid & 1;

    f32x4 acc[4][4] = {};

    int rS[4], cS[4];
    #pragma unroll
    for (int i = 0; i < 4; i++) {
        int ch = wid * 4 + i;
        int r = ch * 8 + (lane >> 3);
        rS[i] = r;
        cS[i] = ((lane & 7) ^ (r & 7)) << 3;
    }

    for (int k0 = 0; k0 < TK; k0 += 64) {
        #pragma unroll
        for (int i = 0; i < 4; i++) {
            int ch = wid * 4 + i;
            const unsigned short* ga = A + (size_t)(row0 + rS[i]) * TK + k0 + cS[i];
            __builtin_amdgcn_global_load_lds((const AS1 unsigned int*)ga,
                                             (AS3 unsigned int*)&sA[ch * 512], 16, 0, 0);
            const unsigned short* gb = Bt + (size_t)(col0 + rS[i]) * TK + k0 + cS[i];
            __builtin_amdgcn_global_load_lds((const AS1 unsigned int*)gb,
                                             (AS3 unsigned int*)&sB[ch * 512], 16, 0, 0);
        }
        __syncthreads();

        #pragma unroll
        for (int kk = 0; kk < 64; kk += 32) {
            int ko = (kk + ((lane >> 4) << 3)) * 2;
            short8v af[4], bf[4];
            #pragma unroll
            for (int m = 0; m < 4; m++) {
                int r = wr * 64 + m * 16 + (lane & 15);
                int addr = r * 128 + (ko ^ ((r & 7) << 4));
                af[m] = *(const short8v*)((const char*)sA + addr);
            }
            #pragma unroll
            for (int n = 0; n < 4; n++) {
                int r = wc * 64 + n * 16 + (lane & 15);
                int addr = r * 128 + (ko ^ ((r & 7) << 4));
                bf[n] = *(const short8v*)((const char*)sB + addr);
            }
            #pragma unroll
            for (int m = 0; m < 4; m++)
                #pragma unroll
                for (int n = 0; n < 4; n++)
                    acc[m][n] = __builtin_amdgcn_mfma_f32_16x16x32_bf16(af[m], bf[n], acc[m][n], 0, 0, 0);
        }
        __syncthreads();
    }

    int crow = (lane >> 4) * 4;
    int ccol = lane & 15;
    #pragma unroll
    for (int m = 0; m < 4; m++) {
        #pragma unroll
        for (int n = 0; n < 4; n++) {
            int gc = col0 + wc * 64 + n * 16 + ccol;
            float bv = bias[gc];
            #pragma unroll
            for (int j = 0; j < 4; j++) {
                int gr = row0 + wr * 64 + m * 16 + crow + j;
                float v = acc[m][n][j] + bv;
                if (OUT_BF16) ((unsigned short*)Cout)[(size_t)gr * N + gc] = f2bf(v);
                else          ((float*)Cout)[(size_t)gr * N + gc] = v;
            }
        }
    }
}

// ---------------- scores GEMM: q2bf[b](128x768) @ K_b^T (raw) -> S0 f32 (64x8192 per b) ----------------
__global__ __launch_bounds__(256) void gemm_scores_kernel(const unsigned short* __restrict__ Aall,
                                                          const unsigned short* __restrict__ kv,
                                                          float* __restrict__ scores) {
    __shared__ unsigned short sA[128 * 64];
    __shared__ unsigned short sB[128 * 64];

    int b = blockIdx.y;
    int col0 = blockIdx.x * 128;
    const unsigned short* A = Aall + (size_t)b * 128 * HIDDEN;
    const unsigned short* Bt = kv + (size_t)b * MSEQ * 1536;

    int tid = threadIdx.x;
    int lane = tid & 63, wid = tid >> 6;
    int wr = wid >> 1, wc = wid & 1;

    f32x4 acc[4][4] = {};

    int rS[4], cS[4];
    #pragma unroll
    for (int i = 0; i < 4; i++) {
        int ch = wid * 4 + i;
        int r = ch * 8 + (lane >> 3);
        rS[i] = r;
        cS[i] = ((lane & 7) ^ (r & 7)) << 3;
    }

    for (int k0 = 0; k0 < HIDDEN; k0 += 64) {
        #pragma unroll
        for (int i = 0; i < 4; i++) {
            int ch = wid * 4 + i;
            const unsigned short* ga = A + (size_t)rS[i] * HIDDEN + k0 + cS[i];
            __builtin_amdgcn_global_load_lds((const AS1 unsigned int*)ga,
                                             (AS3 unsigned int*)&sA[ch * 512], 16, 0, 0);
            const unsigned short* gb = Bt + (size_t)(col0 + rS[i]) * 1536 + k0 + cS[i];
            __builtin_amdgcn_global_load_lds((const AS1 unsigned int*)gb,
                                             (AS3 unsigned int*)&sB[ch * 512], 16, 0, 0);
        }
        __syncthreads();

        #pragma unroll
        for (int kk = 0; kk < 64; kk += 32) {
            int ko = (kk + ((lane >> 4) << 3)) * 2;
            short8v af[4], bf[4];
            #pragma unroll
            for (int m = 0; m < 4; m++) {
                int r = wr * 64 + m * 16 + (lane & 15);
                int addr = r * 128 + (ko ^ ((r & 7) << 4));
                af[m] = *(const short8v*)((const char*)sA + addr);
            }
            #pragma unroll
            for (int n = 0; n < 4; n++) {
                int r = wc * 64 + n * 16 + (lane & 15);
                int addr = r * 128 + (ko ^ ((r & 7) << 4));
                bf[n] = *(const short8v*)((const char*)sB + addr);
            }
            #pragma unroll
            for (int m = 0; m < 4; m++)
                #pragma unroll
                for (int n = 0; n < 4; n++)
                    acc[m][n] = __builtin_amdgcn_mfma_f32_16x16x32_bf16(af[m], bf[n], acc[m][n], 0, 0, 0);
        }
        __syncthreads();
    }

    int crow = (lane >> 4) * 4;
    int ccol = lane & 15;
    #pragma unroll
    for (int m = 0; m < 4; m++) {
        #pragma unroll
        for (int n = 0; n < 4; n++) {
            int gc = col0 + wc * 64 + n * 16 + ccol;
            #pragma unroll
            for (int j = 0; j < 4; j++) {
                int gr = wr * 64 + m * 16 + crow + j;
                if (gr < 64)
                    scores[((size_t)(b * 64 + gr)) * MSEQ + gc] = acc[m][n][j];
            }
        }
    }
}

// ---------------- windowed softmax with LN-fold; also zeros o_acc row ----------------
__global__ __launch_bounds__(512) void win_softmax_kernel(const float* __restrict__ scores,
                                                          const float2* __restrict__ stats,
                                                          const float* __restrict__ qgsum,
                                                          unsigned short* __restrict__ P_abs,
                                                          float* __restrict__ s2out,
                                                          float* __restrict__ o_acc) {
    int bidx = blockIdx.x;
    int b = bidx >> 6, n = bidx & 63;
    int step = (MSEQ - WINSZ) / (NQ - 1);
    int s = n * step;
    if (s + WINSZ > MSEQ) s = MSEQ - WINSZ;

    __shared__ float sm[8];
    int t = threadIdx.x, lane = t & 63, w = t >> 6;

    float* oz = o_acc + ((size_t)(b * 64 + n)) * HIDDEN;
    oz[t] = 0.f;
    if (t < 256) oz[512 + t] = 0.f;

    int r_abs = s + t;
    size_t rowidx = (size_t)b * MSEQ + r_abs;
    float2 stk = stats[rowidx * 2 + 0];
    float qg = qgsum[b * 64 + n];
    float a = stk.y * scores[((size_t)(b * 64 + n)) * MSEQ + r_abs] - qg * stk.x;

    float m = a;
    #pragma unroll
    for (int o = 32; o; o >>= 1) m = fmaxf(m, __shfl_down(m, o));
    if (lane == 0) sm[w] = m;
    __syncthreads();
    m = sm[0];
    #pragma unroll
    for (int i = 1; i < 8; i++) m = fmaxf(m, sm[i]);
    float e = expf(a - m);
    float ssum = e;
    #pragma unroll
    for (int o = 32; o; o >>= 1) ssum += __shfl_down(ssum, o);
    __syncthreads();
    if (lane == 0) sm[w] = ssum;
    __syncthreads();
    ssum = 0;
    #pragma unroll
    for (int i = 0; i < 8; i++) ssum += sm[i];
    float p = e / ssum;

    float2 stv = stats[rowidx * 2 + 1];
    float pt = p * stv.y;
    float s2p = p * stv.x;
    #pragma unroll
    for (int o = 32; o; o >>= 1) s2p += __shfl_down(s2p, o);
    __syncthreads();
    if (lane == 0) sm[w] = s2p;
    __syncthreads();
    if (t == 0) {
        float s2 = 0;
        #pragma unroll
        for (int i = 0; i < 8; i++) s2 += sm[i];
        s2out[b * 64 + n] = s2;
    }

    unsigned short* prow = P_abs + ((size_t)(b * 64 + n)) * MSEQ;
    for (int pos = t; pos < MSEQ; pos += 512)
        if (pos < s || pos >= s + WINSZ) prow[pos] = 0;
    prow[r_abs] = f2bf(pt);
}

// ---------------- PV chunks ----------------
__global__ __launch_bounds__(768) void pv_chunk_kernel(const unsigned short* __restrict__ P_abs,
                                                       const unsigned short* __restrict__ kv,
                                                       float* __restrict__ out_acc) {
    int b = blockIdx.y;
    int r0 = blockIdx.x * 64;
    int t = threadIdx.x;

    int n_lo = (r0 >= 512) ? ((r0 - 512) / 121 + 1) : 0;
    int n_hi = (r0 + 63) / 121;
    if (n_hi > 63) n_hi = 63;

    __shared__ float pw[5][64];
    if (t < 5 * 64) {
        int ni = t >> 6, r = t & 63;
        int n = n_lo + ni;
        float v = 0.f;
        if (n <= n_hi)
            v = bf2f(P_abs[((size_t)(b * 64 + n)) * MSEQ + r0 + r]);
        pw[ni][r] = v;
    }
    __syncthreads();

    const unsigned short* vbase = kv + ((size_t)(b * MSEQ + r0)) * 1536 + 768;
    float acc[5] = {};
    #pragma unroll 8
    for (int r = 0; r < 64; ++r) {
        float v = bf2f(vbase[(size_t)r * 1536 + t]);
        #pragma unroll
        for (int ni = 0; ni < 5; ni++) acc[ni] = fmaf(v, pw[ni][r], acc[ni]);
    }
    #pragma unroll
    for (int ni = 0; ni < 5; ni++) {
        int n = n_lo + ni;
        if (n <= n_hi)
            atomicAdd(&out_acc[((size_t)(b * 64 + n)) * HIDDEN + t], acc[ni]);
    }
}

// ---------------- final affine: a = g*(o_acc - s2) + b ----------------
__global__ __launch_bounds__(256) void out_affine_kernel(const float* __restrict__ o_acc,
                                                         const float* __restrict__ s2,
                                                         const float* __restrict__ g,
                                                         const float* __restrict__ bb,
                                                         unsigned short* __restrict__ a_bf) {
    int i = blockIdx.x * 256 + threadIdx.x;
    if (i >= BATCH * NQ * HIDDEN) return;
    int n = i / HIDDEN, d = i - n * HIDDEN;
    a_bf[i] = f2bf(g[d] * (o_acc[i] - s2[n]) + bb[d]);
}

// ---------------- LN over contiguous 768-rows (f32 in-place) ----------------
__global__ __launch_bounds__(256) void ln_f32_rows(float* __restrict__ base,
                                                   const float* __restrict__ g,
                                                   const float* __restrict__ b) {
    int rh = blockIdx.x;
    float* p = base + (size_t)rh * 768;
    int t = threadIdx.x;
    float x0 = p[t], x1 = p[t + 256], x2 = p[t + 512];
    float s = x0 + x1 + x2, s2 = x0 * x0 + x1 * x1 + x2 * x2;
    __shared__ float sm[8];
    block_reduce2_256(s, s2, sm);
    float mu = s * (1.f / 768.f);
    float var = s2 * (1.f / 768.f) - mu * mu;
    float inv = rsqrtf(var + LN_EPS);
    p[t]       = (x0 - mu) * inv * g[t]       + b[t];
    p[t + 256] = (x1 - mu) * inv * g[t + 256] + b[t + 256];
    p[t + 512] = (x2 - mu) * inv * g[t + 512] + b[t + 512];
}

// ---------------- inst attention with fused K/V LayerNorm (raw f32 kv in, bf16 out) ----------------
__global__ __launch_bounds__(256) void attn_inst_kernel(const float* __restrict__ queries,
                                                        const float* __restrict__ kv,   // raw
                                                        const float* __restrict__ g,
                                                        const float* __restrict__ bb,
                                                        unsigned short* __restrict__ qatt) {
    int bidx = blockIdx.x;
    int b = bidx >> 6, n = bidx & 63;
    __shared__ float qg[HIDDEN];
    __shared__ float sc[LI], sc2[LI];
    __shared__ float2 stv[LI];
    __shared__ float sm[8];
    int t = threadIdx.x, lane = t & 63, w = t >> 6;
    const float* q = queries + (size_t)n * HIDDEN;
    float pgs = 0.f, pqb = 0.f;
    for (int d = t; d < HIDDEN; d += 256) {
        float qd = q[d], gg = g[d];
        qg[d] = qd * gg;
        pgs += qd * gg;
        pqb += qd * bb[d];
    }
    block_reduce2_256(pgs, pqb, sm);
    float qgs = pgs, qb = pqb;

    const float* kb = kv + (size_t)b * LI * 1536;
    for (int j = w; j < LI; j += 4) {
        const float* kr = kb + (size_t)j * 1536;
        const float* vr = kr + 768;
        float dotg = 0, sk = 0, s2k = 0, sv = 0, s2v = 0;
        #pragma unroll
        for (int i = 0; i < 12; i++) {
            int d = lane + i * 64;
            float kd = kr[d], vd = vr[d];
            dotg = fmaf(qg[d], kd, dotg);
            sk += kd; s2k = fmaf(kd, kd, s2k);
            sv += vd; s2v = fmaf(vd, vd, s2v);
        }
        #pragma unroll
        for (int o = 32; o; o >>= 1) {
            dotg += __shfl_down(dotg, o); sk += __shfl_down(sk, o); s2k += __shfl_down(s2k, o);
            sv += __shfl_down(sv, o); s2v += __shfl_down(s2v, o);
        }
        if (lane == 0) {
            float muk = sk * (1.f / 768.f);
            float invk = rsqrtf(s2k * (1.f / 768.f) - muk * muk + LN_EPS);
            sc[j] = SCALE_QK * (invk * dotg - muk * invk * qgs + qb);
            float muv = sv * (1.f / 768.f);
            float invv = rsqrtf(s2v * (1.f / 768.f) - muv * muv + LN_EPS);
            stv[j] = make_float2(muv * invv, invv);
        }
    }
    __syncthreads();
    float m = -1e30f;
    for (int j = 0; j < LI; j++) m = fmaxf(m, sc[j]);
    if (t < LI) sc2[t] = expf(sc[t] - m);
    __syncthreads();
    float s = 0;
    for (int j = 0; j < LI; j++) s += sc2[j];
    float invs = 1.f / s;
    float o0 = 0, o1 = 0, o2 = 0, s2sum = 0;
    for (int j = 0; j < LI; j++) {
        float p = sc2[j] * invs;
        float pt = p * stv[j].y;
        s2sum = fmaf(p, stv[j].x, s2sum);
        const float* vr = kb + (size_t)j * 1536 + 768;
        o0 = fmaf(pt, vr[t], o0);
        o1 = fmaf(pt, vr[t + 256], o1);
        o2 = fmaf(pt, vr[t + 512], o2);
    }
    unsigned short* orow = qatt + ((size_t)b * NQ + n) * HIDDEN;
    orow[t]       = f2bf(g[t]       * (o0 - s2sum) + bb[t]);
    orow[t + 256] = f2bf(g[t + 256] * (o1 - s2sum) + bb[t + 256]);
    orow[t + 512] = f2bf(g[t + 512] * (o2 - s2sum) + bb[t + 512]);
}

// ---------------- host launch ----------------
extern "C" void kernel_launch(void* const* d_in, const int* in_sizes, int n_in,
                              void* d_out, int out_size, void* d_ws, size_t ws_size,
                              hipStream_t stream) {
    (void)in_sizes; (void)n_in; (void)out_size; (void)ws_size;
    const float* x_mm    = (const float*)d_in[0];
    const float* instf   = (const float*)d_in[1];
    const float* queries = (const float*)d_in[2];
    const float* W_proj  = (const float*)d_in[3];
    const float* b_proj  = (const float*)d_in[4];
    const float* W_kvi   = (const float*)d_in[5];
    const float* b_kvi   = (const float*)d_in[6];
    const float* W_oi    = (const float*)d_in[7];
    const float* b_oi    = (const float*)d_in[8];
    const float* W_kvm   = (const float*)d_in[9];
    const float* b_kvm   = (const float*)d_in[10];
    const float* W_om    = (const float*)d_in[11];
    const float* b_om    = (const float*)d_in[12];
    const float* ln_g    = (const float*)d_in[13];
    const float* ln_b    = (const float*)d_in[14];
    float* out = (float*)d_out;

    char* ws = (char*)d_ws;
    size_t off = 0;
    auto carve = [&](size_t bytes) -> char* {
        char* p = ws + off;
        off += (bytes + 255) & ~(size_t)255;
        return p;
    };
    unsigned short* x_bf   = (unsigned short*)carve((size_t)BATCH * MSEQ * MMHID * 2);
    unsigned short* wtm_bf = (unsigned short*)carve((size_t)2 * HIDDEN * MMHID * 2);
    unsigned short* kv_mm  = (unsigned short*)carve((size_t)BATCH * MSEQ * 2 * HIDDEN * 2);
    unsigned short* wp_bf  = (unsigned short*)carve((size_t)768 * 768 * 2);
    unsigned short* wkvi_bf= (unsigned short*)carve((size_t)1536 * 768 * 2);
    unsigned short* woi_bf = (unsigned short*)carve((size_t)768 * 768 * 2);
    unsigned short* wom_bf = (unsigned short*)carve((size_t)768 * 768 * 2);
    unsigned short* a1_bf  = (unsigned short*)carve((size_t)384 * 768 * 2);
    unsigned short* inst_bf= (unsigned short*)carve((size_t)384 * 768 * 2);
    float*          kv_inst= (float*)carve((size_t)384 * 1536 * 4);
    unsigned short* qatt_bf= (unsigned short*)carve((size_t)256 * 768 * 2);
    float*          q2     = (float*)carve((size_t)256 * 768 * 4);
    unsigned short* q2bf   = (unsigned short*)carve((size_t)BATCH * 128 * 768 * 2);
    float*          scores = (float*)carve((size_t)BATCH * 64 * MSEQ * 4);
    unsigned short* P_abs  = (unsigned short*)carve((size_t)BATCH * 64 * MSEQ * 2);
    float*          o_acc  = (float*)carve((size_t)BATCH * 64 * 768 * 4);
    unsigned short* a_bf   = (unsigned short*)carve((size_t)256 * 768 * 2);
    float2*         stats  = (float2*)carve((size_t)BATCH * MSEQ * 2 * sizeof(float2));
    float2*         stat_s = (float2*)carve((size_t)BATCH * MSEQ * 2 * 3 * sizeof(float2));
    float*          qgsum  = (float*)carve((size_t)256 * 4);
    float*          s2     = (float*)carve((size_t)256 * 4);

    // ---- prep: 5 weight transposes + instf cvt (z=5) + x cvt (z=6,7 grid-stride), single dispatch ----
    PrepJobs tw;
    tw.W[0] = W_kvm;  tw.Wt[0] = wtm_bf;  tw.D[0] = 1024; tw.C[0] = 1536;
    tw.W[1] = W_proj; tw.Wt[1] = wp_bf;   tw.D[1] = 768;  tw.C[1] = 768;
    tw.W[2] = W_kvi;  tw.Wt[2] = wkvi_bf; tw.D[2] = 768;  tw.C[2] = 1536;
    tw.W[3] = W_oi;   tw.Wt[3] = woi_bf;  tw.D[3] = 768;  tw.C[3] = 768;
    tw.W[4] = W_om;   tw.Wt[4] = wom_bf;  tw.D[4] = 768;  tw.C[4] = 768;
    tw.inst_in = instf; tw.inst_out = a1_bf;
    tw.n8_valid = BATCH * LI * 768 / 8; tw.n8_total = 384 * 768 / 8;
    tw.x_in = x_mm; tw.x_out = x_bf; tw.n8x = BATCH * MSEQ * MMHID / 8;
    prep_kernel<<<dim3(48, 32, 8), 256, 0, stream>>>(tw);

    // ---- mm branch: 256^2 double-buffered GEMM + atomic-free stat partials -> stats_fin ----
    hipError_t attr_ok = hipFuncSetAttribute((const void*)gemm_kv256_kernel,
                                             hipFuncAttributeMaxDynamicSharedMemorySize, 131072);
    if (attr_ok == hipSuccess) {
        gemm_kv256_kernel<<<(GM / 256) * (GN / 256), 512, 131072, stream>>>(x_bf, wtm_bf, b_kvm, kv_mm, stat_s);
        stats_fin_kernel<<<(BATCH * MSEQ * 2 + 255) / 256, 256, 0, stream>>>(stat_s, stats, BATCH * MSEQ * 2);
    } else {
        gemm_kv128_kernel<<<(GM / 128) * (GN / 128), 256, 0, stream>>>(x_bf, wtm_bf, b_kvm, kv_mm);
        stats_kernel<<<BATCH * MSEQ * 2, 256, 0, stream>>>(kv_mm, stats);
    }

    // ---- inst branch (bf16 MFMA; LN of kv_inst folded into attn) ----
    gemm_tile_kernel<768, true><<<dim3(3, 6), 256, 0, stream>>>(a1_bf, wp_bf, b_proj, inst_bf, 768);
    gemm_tile_kernel<768, false><<<dim3(3, 12), 256, 0, stream>>>(inst_bf, wkvi_bf, b_kvi, kv_inst, 1536);
    attn_inst_kernel<<<BATCH * NQ, 256, 0, stream>>>(queries, kv_inst, ln_g, ln_b, qatt_bf);
    gemm_tile_kernel<768, false><<<dim3(2, 6), 256, 0, stream>>>(qatt_bf, woi_bf, b_oi, q2, 768);

    // ---- windowed attention ----
    cvt_q_kernel<<<BATCH * 128, 256, 0, stream>>>(q2, ln_g, ln_b, q2bf, qgsum);
    gemm_scores_kernel<<<dim3(MSEQ / 128, BATCH), 256, 0, stream>>>(q2bf, kv_mm, scores);
    win_softmax_kernel<<<BATCH * NQ, 512, 0, stream>>>(scores, stats, qgsum, P_abs, s2, o_acc);
    pv_chunk_kernel<<<dim3(MSEQ / 64, BATCH), 768, 0, stream>>>(P_abs, kv_mm, o_acc);
    out_affine_kernel<<<(BATCH * NQ * HIDDEN + 255) / 256, 256, 0, stream>>>(o_acc, s2, ln_g, ln_b, a_bf);

    // ---- output projection ----
    gemm_tile_kernel<768, false><<<dim3(2, 6), 256, 0, stream>>>(a_bf, wom_bf, b_om, out, 768);
    ln_f32_rows<<<BATCH * NQ, 256, 0, stream>>>(out, ln_g, ln_b);
}

// Round 16
// 302.512 us; speedup vs baseline: 1.0003x; 1.0003x over previous
//
#include <hip/hip_runtime.h>

#define HIDDEN 768
#define NQ 64
#define WINSZ 512
#define MSEQ 8192
#define BATCH 4
#define LI 77
#define MMHID 1024
#define LN_EPS 1e-5f
#define SCALE_QK 0.03608439182435161f  // 1/sqrt(768)

typedef __attribute__((ext_vector_type(8))) short short8v;
typedef __attribute__((ext_vector_type(4))) float f32x4;
typedef __attribute__((ext_vector_type(8))) unsigned short u16x8;

#define AS1 __attribute__((address_space(1)))
#define AS3 __attribute__((address_space(3)))

__device__ inline unsigned short f2bf(float f) {
    unsigned u = __float_as_uint(f);
    u += 0x7fffu + ((u >> 16) & 1u);
    return (unsigned short)(u >> 16);
}
__device__ inline float bf2f(unsigned short h) {
    return __uint_as_float(((unsigned)h) << 16);
}

// ---------------- block reduce (256 threads, 4 waves) ----------------
__device__ inline void block_reduce2_256(float& s1, float& s2, float* sm) {
    #pragma unroll
    for (int o = 32; o; o >>= 1) { s1 += __shfl_down(s1, o); s2 += __shfl_down(s2, o); }
    int lane = threadIdx.x & 63, w = threadIdx.x >> 6;
    __syncthreads();
    if (lane == 0) { sm[w] = s1; sm[4 + w] = s2; }
    __syncthreads();
    s1 = sm[0] + sm[1] + sm[2] + sm[3];
    s2 = sm[4] + sm[5] + sm[6] + sm[7];
}

// ---- q2 f32 (pre-LN) -> LN -> q2bf bf16 (4x128x768) with g*SCALE folded; qgsum per row ----
__global__ __launch_bounds__(256) void cvt_q_kernel(const float* __restrict__ q2,
                                                    const float* __restrict__ g,
                                                    const float* __restrict__ bb,
                                                    unsigned short* __restrict__ q2bf,
                                                    float* __restrict__ qgsum) {
    int blk = blockIdx.x;               // b*128 + r
    int b = blk >> 7, r = blk & 127;
    int t = threadIdx.x;
    __shared__ float sm[8];
    unsigned short* orow = q2bf + (size_t)blk * HIDDEN;
    if (r >= 64) {
        orow[t] = 0; orow[t + 256] = 0; orow[t + 512] = 0;
        return;
    }
    const float* qrow = q2 + ((size_t)(b * 64 + r)) * HIDDEN;
    float y0 = qrow[t], y1 = qrow[t + 256], y2 = qrow[t + 512];
    float s = y0 + y1 + y2, s2 = y0 * y0 + y1 * y1 + y2 * y2;
    block_reduce2_256(s, s2, sm);
    float mu = s * (1.f / 768.f);
    float var = s2 * (1.f / 768.f) - mu * mu;
    float inv = rsqrtf(var + LN_EPS);
    float qw0 = (y0 - mu) * inv * g[t]       + bb[t];
    float qw1 = (y1 - mu) * inv * g[t + 256] + bb[t + 256];
    float qw2 = (y2 - mu) * inv * g[t + 512] + bb[t + 512];
    float v0 = qw0 * g[t]       * SCALE_QK;
    float v1 = qw1 * g[t + 256] * SCALE_QK;
    float v2 = qw2 * g[t + 512] * SCALE_QK;
    orow[t] = f2bf(v0); orow[t + 256] = f2bf(v1); orow[t + 512] = f2bf(v2);
    float qs = v0 + v1 + v2, dummy = 0.f;
    block_reduce2_256(qs, dummy, sm);
    if (t == 0) qgsum[b * 64 + r] = qs;
}

// ---------------- prep kernel: 5 weight transposes + instf cvt (z=5) + x cvt (z=6,7 grid-stride) ----------------
struct PrepJobs {
    const float* W[5];
    unsigned short* Wt[5];
    int D[5];
    int C[5];
    const float* inst_in;
    unsigned short* inst_out;
    int n8_valid;
    int n8_total;
    const float* x_in;
    unsigned short* x_out;
    int n8x;
};
__global__ __launch_bounds__(256) void prep_kernel(PrepJobs tw) {
    int z = blockIdx.z;
    if (z >= 6) {
        int per_slice = (int)(gridDim.x * gridDim.y);
        int flat = blockIdx.y * gridDim.x + blockIdx.x;
        int i0 = ((z - 6) * per_slice + flat) * 256 + threadIdx.x;
        int stride = 2 * per_slice * 256;
        for (int i = i0; i < tw.n8x; i += stride) {
            const float4* p = (const float4*)(tw.x_in + (size_t)i * 8);
            float4 a = p[0], b = p[1];
            u16x8 o;
            o[0] = f2bf(a.x); o[1] = f2bf(a.y); o[2] = f2bf(a.z); o[3] = f2bf(a.w);
            o[4] = f2bf(b.x); o[5] = f2bf(b.y); o[6] = f2bf(b.z); o[7] = f2bf(b.w);
            *(u16x8*)(tw.x_out + (size_t)i * 8) = o;
        }
        return;
    }
    if (z == 5) {
        int flat = blockIdx.y * gridDim.x + blockIdx.x;
        int i = flat * 256 + threadIdx.x;
        if (i >= tw.n8_total) return;
        u16x8 o = {};
        if (i < tw.n8_valid) {
            const float4* p = (const float4*)(tw.inst_in + (size_t)i * 8);
            float4 a = p[0], b = p[1];
            o[0] = f2bf(a.x); o[1] = f2bf(a.y); o[2] = f2bf(a.z); o[3] = f2bf(a.w);
            o[4] = f2bf(b.x); o[5] = f2bf(b.y); o[6] = f2bf(b.z); o[7] = f2bf(b.w);
        }
        *(u16x8*)(tw.inst_out + (size_t)i * 8) = o;
        return;
    }
    int C = tw.C[z], D = tw.D[z];
    int n0 = blockIdx.x * 32, k0 = blockIdx.y * 32;
    if (n0 >= C || k0 >= D) return;
    const float* W = tw.W[z];
    unsigned short* Wt = tw.Wt[z];
    __shared__ float tile[32][33];
    int tx = threadIdx.x & 31, ty = (threadIdx.x >> 5);  // 32x8
    #pragma unroll
    for (int i = 0; i < 32; i += 8)
        tile[ty + i][tx] = W[(size_t)(k0 + ty + i) * C + n0 + tx];
    __syncthreads();
    #pragma unroll
    for (int i = 0; i < 32; i += 8)
        Wt[(size_t)(n0 + ty + i) * D + k0 + tx] = f2bf(tile[tx][ty + i]);
}

#define GM 32768
#define GN 1536
#define GK 1024

// ---------------- big GEMM: 256x256 tile, 8 waves, double-buffered 128KB LDS (R12 schedule) ----------------
// R16: stat partials stored SoA-by-slice: stat_s[(tilei*2+half)*GM + gr] -> consecutive
// tid write contiguous float2s (coalesced), killing the 48B-stride RMW amplification.
__global__ __launch_bounds__(512, 2) void gemm_kv256_kernel(const unsigned short* __restrict__ A,
                                                            const unsigned short* __restrict__ Bt,
                                                            const float* __restrict__ bias,
                                                            unsigned short* __restrict__ C,
                                                            float2* __restrict__ stat_s) {
    extern __shared__ char smem[];
    unsigned short* sA = (unsigned short*)smem;            // [2][256*64]
    unsigned short* sB = (unsigned short*)(smem + 65536);  // [2][256*64]

    int nwg = gridDim.x;                                   // 768
    int bid = blockIdx.x;
    int wg = bid;
    if ((nwg & 7) == 0) { int cpx = nwg >> 3; wg = (bid & 7) * cpx + (bid >> 3); }
    int bm = wg / (GN / 256), bn = wg % (GN / 256);
    int row0 = bm * 256, col0 = bn * 256;

    int tid = threadIdx.x;
    int lane = tid & 63, wid = tid >> 6;
    int wm = wid >> 2, wn = wid & 3;                       // 2M x 4N

    f32x4 acc[8][4] = {};

    int rS[4], cS[4];
    #pragma unroll
    for (int i = 0; i < 4; i++) {
        int ch = wid * 4 + i;
        int r = ch * 8 + (lane >> 3);
        rS[i] = r;
        cS[i] = ((lane & 7) ^ (r & 7)) << 3;
    }

    auto STAGE = [&](int k0, int pbuf) {
        unsigned short* dA = sA + pbuf * 16384;
        unsigned short* dB = sB + pbuf * 16384;
        #pragma unroll
        for (int i = 0; i < 4; i++) {
            int ch = wid * 4 + i;
            const unsigned short* ga = A + (size_t)(row0 + rS[i]) * GK + k0 + cS[i];
            __builtin_amdgcn_global_load_lds((const AS1 unsigned int*)ga,
                                             (AS3 unsigned int*)&dA[ch * 512], 16, 0, 0);
            const unsigned short* gb = Bt + (size_t)(col0 + rS[i]) * GK + k0 + cS[i];
            __builtin_amdgcn_global_load_lds((const AS1 unsigned int*)gb,
                                             (AS3 unsigned int*)&dB[ch * 512], 16, 0, 0);
        }
    };

    STAGE(0, 0);
    __syncthreads();

    for (int kt = 0; kt < GK / 64; kt++) {
        int cur = kt & 1;
        if (kt < GK / 64 - 1) STAGE((kt + 1) * 64, cur ^ 1);

        const char* lA = (const char*)(sA + cur * 16384);
        const char* lB = (const char*)(sB + cur * 16384);

        short8v bfr[4][2];
        #pragma unroll
        for (int n = 0; n < 4; n++)
            #pragma unroll
            for (int kk = 0; kk < 2; kk++) {
                int r = wn * 64 + n * 16 + (lane & 15);
                int ko = (kk * 32 + ((lane >> 4) << 3)) * 2;
                bfr[n][kk] = *(const short8v*)(lB + r * 128 + (ko ^ ((r & 7) << 4)));
            }
        #pragma unroll
        for (int p = 0; p < 4; p++) {
            short8v afr[2][2];
            #pragma unroll
            for (int mf = 0; mf < 2; mf++)
                #pragma unroll
                for (int kk = 0; kk < 2; kk++) {
                    int r = wm * 128 + (p * 2 + mf) * 16 + (lane & 15);
                    int ko = (kk * 32 + ((lane >> 4) << 3)) * 2;
                    afr[mf][kk] = *(const short8v*)(lA + r * 128 + (ko ^ ((r & 7) << 4)));
                }
            __builtin_amdgcn_s_setprio(1);
            #pragma unroll
            for (int mf = 0; mf < 2; mf++)
                #pragma unroll
                for (int n = 0; n < 4; n++)
                    #pragma unroll
                    for (int kk = 0; kk < 2; kk++)
                        acc[p * 2 + mf][n] = __builtin_amdgcn_mfma_f32_16x16x32_bf16(
                            afr[mf][kk], bfr[n][kk], acc[p * 2 + mf][n], 0, 0, 0);
            __builtin_amdgcn_s_setprio(0);
        }
        __syncthreads();
    }

    // ---- epilogue: bias + bf16 store + per-row {sum, sumsq} partials (atomic-free, coalesced) ----
    float2* rowpart = (float2*)smem;   // [4][256] = 8 KB; LDS free after final barrier

    int crow = (lane >> 4) * 4;
    int ccol = lane & 15;
    int half = (col0 >= 768) ? 1 : 0;
    int tilei = (col0 - half * 768) >> 8;   // 0..2
    #pragma unroll
    for (int m = 0; m < 8; m++) {
        float rs[4] = {}, rq[4] = {};
        #pragma unroll
        for (int n = 0; n < 4; n++) {
            int gc = col0 + wn * 64 + n * 16 + ccol;
            float bv = bias[gc];
            #pragma unroll
            for (int j = 0; j < 4; j++) {
                int gr = row0 + wm * 128 + m * 16 + crow + j;
                float v = acc[m][n][j] + bv;
                C[(size_t)gr * GN + gc] = f2bf(v);
                rs[j] += v; rq[j] += v * v;
            }
        }
        #pragma unroll
        for (int j = 0; j < 4; j++) {
            float s_ = rs[j], q_ = rq[j];
            #pragma unroll
            for (int o = 8; o; o >>= 1) { s_ += __shfl_xor(s_, o); q_ += __shfl_xor(q_, o); }
            if (ccol == 0) {
                int lr = wm * 128 + m * 16 + crow + j;   // local row 0..255, unique per (wn, lr)
                rowpart[wn * 256 + lr] = make_float2(s_, q_);
            }
        }
    }
    __syncthreads();
    if (tid < 256) {
        float2 a0 = rowpart[tid], a1 = rowpart[256 + tid];
        float2 a2 = rowpart[512 + tid], a3 = rowpart[768 + tid];
        int gr = row0 + tid;
        // SoA by (tilei, half): contiguous per-block store stream
        stat_s[((size_t)(tilei * 2 + half)) * GM + gr] =
            make_float2(a0.x + a1.x + a2.x + a3.x, a0.y + a1.y + a2.y + a3.y);
    }
}

// ---------------- finalize stats: sum 3 col-tile slices -> {mu*inv, inv} ----------------
// i = gr*2 + half (matches stats[] consumer layout)
__global__ __launch_bounds__(256) void stats_fin_kernel(const float2* __restrict__ part,
                                                        float2* __restrict__ stats, int n) {
    int i = blockIdx.x * 256 + threadIdx.x;
    if (i >= n) return;
    int gr = i >> 1, half = i & 1;
    float2 a0 = part[((size_t)(0 * 2 + half)) * GM + gr];
    float2 a1 = part[((size_t)(1 * 2 + half)) * GM + gr];
    float2 a2 = part[((size_t)(2 * 2 + half)) * GM + gr];
    float sx = a0.x + a1.x + a2.x;
    float sq = a0.y + a1.y + a2.y;
    float mu = sx * (1.f / 768.f);
    float var = sq * (1.f / 768.f) - mu * mu;
    float inv = rsqrtf(var + LN_EPS);
    stats[i] = make_float2(mu * inv, inv);
}

// ---------------- fallback: 128x128 GEMM (R8-verified, no stats) ----------------
__global__ __launch_bounds__(256) void gemm_kv128_kernel(const unsigned short* __restrict__ A,
                                                         const unsigned short* __restrict__ Bt,
                                                         const float* __restrict__ bias,
                                                         unsigned short* __restrict__ C) {
    __shared__ unsigned short sA[128 * 64];
    __shared__ unsigned short sB[128 * 64];

    int nwg = gridDim.x;
    int bid = blockIdx.x;
    int wg = bid;
    if ((nwg & 7) == 0) { int cpx = nwg >> 3; wg = (bid & 7) * cpx + (bid >> 3); }
    int bm = wg / (GN / 128), bn = wg % (GN / 128);
    int row0 = bm * 128, col0 = bn * 128;

    int tid = threadIdx.x;
    int lane = tid & 63, wid = tid >> 6;
    int wr = wid >> 1, wc = wid & 1;

    f32x4 acc[4][4] = {};

    int rS[4], cS[4];
    #pragma unroll
    for (int i = 0; i < 4; i++) {
        int ch = wid * 4 + i;
        int r = ch * 8 + (lane >> 3);
        rS[i] = r;
        cS[i] = ((lane & 7) ^ (r & 7)) << 3;
    }

    for (int k0 = 0; k0 < GK; k0 += 64) {
        #pragma unroll
        for (int i = 0; i < 4; i++) {
            int ch = wid * 4 + i;
            const unsigned short* ga = A + (size_t)(row0 + rS[i]) * GK + k0 + cS[i];
            __builtin_amdgcn_global_load_lds((const AS1 unsigned int*)ga,
                                             (AS3 unsigned int*)&sA[ch * 512], 16, 0, 0);
            const unsigned short* gb = Bt + (size_t)(col0 + rS[i]) * GK + k0 + cS[i];
            __builtin_amdgcn_global_load_lds((const AS1 unsigned int*)gb,
                                             (AS3 unsigned int*)&sB[ch * 512], 16, 0, 0);
        }
        __syncthreads();

        #pragma unroll
        for (int kk = 0; kk < 64; kk += 32) {
            int ko = (kk + ((lane >> 4) << 3)) * 2;
            short8v af[4], bf[4];
            #pragma unroll
            for (int m = 0; m < 4; m++) {
                int r = wr * 64 + m * 16 + (lane & 15);
                int addr = r * 128 + (ko ^ ((r & 7) << 4));
                af[m] = *(const short8v*)((const char*)sA + addr);
            }
            #pragma unroll
            for (int n = 0; n < 4; n++) {
                int r = wc * 64 + n * 16 + (lane & 15);
                int addr = r * 128 + (ko ^ ((r & 7) << 4));
                bf[n] = *(const short8v*)((const char*)sB + addr);
            }
            #pragma unroll
            for (int m = 0; m < 4; m++)
                #pragma unroll
                for (int n = 0; n < 4; n++)
                    acc[m][n] = __builtin_amdgcn_mfma_f32_16x16x32_bf16(af[m], bf[n], acc[m][n], 0, 0, 0);
        }
        __syncthreads();
    }

    int crow = (lane >> 4) * 4;
    int ccol = lane & 15;
    #pragma unroll
    for (int m = 0; m < 4; m++) {
        #pragma unroll
        for (int n = 0; n < 4; n++) {
            int gc = col0 + wc * 64 + n * 16 + ccol;
            float bv = bias[gc];
            #pragma unroll
            for (int j = 0; j < 4; j++) {
                int gr = row0 + wr * 64 + m * 16 + crow + j;
                C[(size_t)gr * GN + gc] = f2bf(acc[m][n][j] + bv);
            }
        }
    }
}

// ---------------- per-row-half LN stats from raw bf16 kv (fallback path only) ----------------
__global__ __launch_bounds__(256) void stats_kernel(const unsigned short* __restrict__ kv,
                                                    float2* __restrict__ stats) {
    int rh = blockIdx.x;
    const unsigned short* p = kv + (size_t)rh * 768;
    int t = threadIdx.x;
    float x0 = bf2f(p[t]), x1 = bf2f(p[t + 256]), x2 = bf2f(p[t + 512]);
    float s = x0 + x1 + x2, s2 = x0 * x0 + x1 * x1 + x2 * x2;
    __shared__ float sm[8];
    block_reduce2_256(s, s2, sm);
    if (t == 0) {
        float mu = s * (1.f / 768.f);
        float var = s2 * (1.f / 768.f) - mu * mu;
        float inv = rsqrtf(var + LN_EPS);
        stats[rh] = make_float2(mu * inv, inv);
    }
}

// ---------------- generic small MFMA GEMM: A(Mp x TK)bf16 @ Bt(N x TK)^T + bias ----------------
template <int TK, bool OUT_BF16>
__global__ __launch_bounds__(256) void gemm_tile_kernel(const unsigned short* __restrict__ A,
                                                        const unsigned short* __restrict__ Bt,
                                                        const float* __restrict__ bias,
                                                        void* __restrict__ Cout, int N) {
    __shared__ unsigned short sA[128 * 64];
    __shared__ unsigned short sB[128 * 64];

    int row0 = blockIdx.x * 128, col0 = blockIdx.y * 128;
    int tid = threadIdx.x;
    int lane = tid & 63, wid = tid >> 6;
    int wr = wid >> 1, wc = wid & 1;

    f32x4 acc[4][4] = {};

    int rS[4], cS[4];
    #pragma unroll
    for (int i = 0; i < 4; i++) {
        int ch = wid * 4 + i;
        int r = ch * 8 + (lane >> 3);
        rS[i] = r;
        cS[i] = ((lane & 7) ^ (r & 7)) << 3;
    }

    for (int k0 = 0; k0 < TK; k0 += 64) {
        #pragma unroll
        for (int i = 0; i < 4; i++) {
            int ch = wid * 4 + i;
            const unsigned short* ga = A + (size_t)(row0 + rS[i]) * TK + k0 + cS[i];
            __builtin_amdgcn_global_load_lds((const AS1 unsigned int*)ga,
                                             (AS3 unsigned int*)&sA[ch * 512], 16, 0, 0);
            const unsigned short* gb = Bt + (size_t)(col0 + rS[i]) * TK + k0 + cS[i];
            __builtin_amdgcn_global_load_lds((const AS1 unsigned int*)gb,
                                             (AS3 unsigned int*)&sB[ch * 512], 16, 0, 0);
        }
        __syncthreads();

        #pragma unroll
        for (int kk = 0; kk < 64; kk += 32) {
            int ko = (kk + ((lane >> 4) << 3)) * 2;
            short8v af[4], bf[4];
            #pragma unroll
            for (int m = 0; m < 4; m++) {
                int r = wr * 64 + m * 16 + (lane & 15);
                int addr = r * 128 + (ko ^ ((r & 7) << 4));
                af[m] = *(const short8v*)((const char*)sA + addr);
            }
            #pragma unroll
            for (int n = 0; n < 4; n++) {
                int r = wc * 64 + n * 16 + (lane & 15);
                int addr = r * 128 + (ko ^ ((r & 7) << 4));
                bf[n] = *(const short8v*)((const char*)sB + addr);
            }
            #pragma unroll
            for (int m = 0; m < 4; m++)
                #pragma unroll
                for (int n = 0; n < 4; n++)
                    acc[m][n] = __builtin_amdgcn_mfma_f32_16x16x32_bf16(af[m], bf[n], acc[m][n], 0, 0, 0);
        }
        __syncthreads();
    }

    int crow = (lane >> 4) * 4;
    int ccol = lane & 15;
    #pragma unroll
    for (int m = 0; m < 4; m++) {
        #pragma unroll
        for (int n = 0; n < 4; n++) {
            int gc = col0 + wc * 64 + n * 16 + ccol;
            float bv = bias[gc];
            #pragma unroll
            for (int j = 0; j < 4; j++) {
                int gr = row0 + wr * 64 + m * 16 + crow + j;
                float v = acc[m][n][j] + bv;
                if (OUT_BF16) ((unsigned short*)Cout)[(size_t)gr * N + gc] = f2bf(v);
                else          ((float*)Cout)[(size_t)gr * N + gc] = v;
            }
        }
    }
}

// ---------------- scores GEMM: q2bf[b](128x768) @ K_b^T (raw) -> S0 f32 (64x8192 per b) ----------------
__global__ __launch_bounds__(256) void gemm_scores_kernel(const unsigned short* __restrict__ Aall,
                                                          const unsigned short* __restrict__ kv,
                                                          float* __restrict__ scores) {
    __shared__ unsigned short sA[128 * 64];
    __shared__ unsigned short sB[128 * 64];

    int b = blockIdx.y;
    int col0 = blockIdx.x * 128;
    const unsigned short* A = Aall + (size_t)b * 128 * HIDDEN;
    const unsigned short* Bt = kv + (size_t)b * MSEQ * 1536;

    int tid = threadIdx.x;
    int lane = tid & 63, wid = tid >> 6;
    int wr = wid >> 1, wc = wid & 1;

    f32x4 acc[4][4] = {};

    int rS[4], cS[4];
    #pragma unroll
    for (int i = 0; i < 4; i++) {
        int ch = wid * 4 + i;
        int r = ch * 8 + (lane >> 3);
        rS[i] = r;
        cS[i] = ((lane & 7) ^ (r & 7)) << 3;
    }

    for (int k0 = 0; k0 < HIDDEN; k0 += 64) {
        #pragma unroll
        for (int i = 0; i < 4; i++) {
            int ch = wid * 4 + i;
            const unsigned short* ga = A + (size_t)rS[i] * HIDDEN + k0 + cS[i];
            __builtin_amdgcn_global_load_lds((const AS1 unsigned int*)ga,
                                             (AS3 unsigned int*)&sA[ch * 512], 16, 0, 0);
            const unsigned short* gb = Bt + (size_t)(col0 + rS[i]) * 1536 + k0 + cS[i];
            __builtin_amdgcn_global_load_lds((const AS1 unsigned int*)gb,
                                             (AS3 unsigned int*)&sB[ch * 512], 16, 0, 0);
        }
        __syncthreads();

        #pragma unroll
        for (int kk = 0; kk < 64; kk += 32) {
            int ko = (kk + ((lane >> 4) << 3)) * 2;
            short8v af[4], bf[4];
            #pragma unroll
            for (int m = 0; m < 4; m++) {
                int r = wr * 64 + m * 16 + (lane & 15);
                int addr = r * 128 + (ko ^ ((r & 7) << 4));
                af[m] = *(const short8v*)((const char*)sA + addr);
            }
            #pragma unroll
            for (int n = 0; n < 4; n++) {
                int r = wc * 64 + n * 16 + (lane & 15);
                int addr = r * 128 + (ko ^ ((r & 7) << 4));
                bf[n] = *(const short8v*)((const char*)sB + addr);
            }
            #pragma unroll
            for (int m = 0; m < 4; m++)
                #pragma unroll
                for (int n = 0; n < 4; n++)
                    acc[m][n] = __builtin_amdgcn_mfma_f32_16x16x32_bf16(af[m], bf[n], acc[m][n], 0, 0, 0);
        }
        __syncthreads();
    }

    int crow = (lane >> 4) * 4;
    int ccol = lane & 15;
    #pragma unroll
    for (int m = 0; m < 4; m++) {
        #pragma unroll
        for (int n = 0; n < 4; n++) {
            int gc = col0 + wc * 64 + n * 16 + ccol;
            #pragma unroll
            for (int j = 0; j < 4; j++) {
                int gr = wr * 64 + m * 16 + crow + j;
                if (gr < 64)
                    scores[((size_t)(b * 64 + gr)) * MSEQ + gc] = acc[m][n][j];
            }
        }
    }
}

// ---------------- windowed softmax with LN-fold; also zeros o_acc row ----------------
__global__ __launch_bounds__(512) void win_softmax_kernel(const float* __restrict__ scores,
                                                          const float2* __restrict__ stats,
                                                          const float* __restrict__ qgsum,
                                                          unsigned short* __restrict__ P_abs,
                                                          float* __restrict__ s2out,
                                                          float* __restrict__ o_acc) {
    int bidx = blockIdx.x;
    int b = bidx >> 6, n = bidx & 63;
    int step = (MSEQ - WINSZ) / (NQ - 1);
    int s = n * step;
    if (s + WINSZ > MSEQ) s = MSEQ - WINSZ;

    __shared__ float sm[8];
    int t = threadIdx.x, lane = t & 63, w = t >> 6;

    float* oz = o_acc + ((size_t)(b * 64 + n)) * HIDDEN;
    oz[t] = 0.f;
    if (t < 256) oz[512 + t] = 0.f;

    int r_abs = s + t;
    size_t rowidx = (size_t)b * MSEQ + r_abs;
    float2 stk = stats[rowidx * 2 + 0];
    float qg = qgsum[b * 64 + n];
    float a = stk.y * scores[((size_t)(b * 64 + n)) * MSEQ + r_abs] - qg * stk.x;

    float m = a;
    #pragma unroll
    for (int o = 32; o; o >>= 1) m = fmaxf(m, __shfl_down(m, o));
    if (lane == 0) sm[w] = m;
    __syncthreads();
    m = sm[0];
    #pragma unroll
    for (int i = 1; i < 8; i++) m = fmaxf(m, sm[i]);
    float e = expf(a - m);
    float ssum = e;
    #pragma unroll
    for (int o = 32; o; o >>= 1) ssum += __shfl_down(ssum, o);
    __syncthreads();
    if (lane == 0) sm[w] = ssum;
    __syncthreads();
    ssum = 0;
    #pragma unroll
    for (int i = 0; i < 8; i++) ssum += sm[i];
    float p = e / ssum;

    float2 stv = stats[rowidx * 2 + 1];
    float pt = p * stv.y;
    float s2p = p * stv.x;
    #pragma unroll
    for (int o = 32; o; o >>= 1) s2p += __shfl_down(s2p, o);
    __syncthreads();
    if (lane == 0) sm[w] = s2p;
    __syncthreads();
    if (t == 0) {
        float s2 = 0;
        #pragma unroll
        for (int i = 0; i < 8; i++) s2 += sm[i];
        s2out[b * 64 + n] = s2;
    }

    unsigned short* prow = P_abs + ((size_t)(b * 64 + n)) * MSEQ;
    for (int pos = t; pos < MSEQ; pos += 512)
        if (pos < s || pos >= s + WINSZ) prow[pos] = 0;
    prow[r_abs] = f2bf(pt);
}

// ---------------- PV chunks ----------------
__global__ __launch_bounds__(768) void pv_chunk_kernel(const unsigned short* __restrict__ P_abs,
                                                       const unsigned short* __restrict__ kv,
                                                       float* __restrict__ out_acc) {
    int b = blockIdx.y;
    int r0 = blockIdx.x * 64;
    int t = threadIdx.x;

    int n_lo = (r0 >= 512) ? ((r0 - 512) / 121 + 1) : 0;
    int n_hi = (r0 + 63) / 121;
    if (n_hi > 63) n_hi = 63;

    __shared__ float pw[5][64];
    if (t < 5 * 64) {
        int ni = t >> 6, r = t & 63;
        int n = n_lo + ni;
        float v = 0.f;
        if (n <= n_hi)
            v = bf2f(P_abs[((size_t)(b * 64 + n)) * MSEQ + r0 + r]);
        pw[ni][r] = v;
    }
    __syncthreads();

    const unsigned short* vbase = kv + ((size_t)(b * MSEQ + r0)) * 1536 + 768;
    float acc[5] = {};
    #pragma unroll 8
    for (int r = 0; r < 64; ++r) {
        float v = bf2f(vbase[(size_t)r * 1536 + t]);
        #pragma unroll
        for (int ni = 0; ni < 5; ni++) acc[ni] = fmaf(v, pw[ni][r], acc[ni]);
    }
    #pragma unroll
    for (int ni = 0; ni < 5; ni++) {
        int n = n_lo + ni;
        if (n <= n_hi)
            atomicAdd(&out_acc[((size_t)(b * 64 + n)) * HIDDEN + t], acc[ni]);
    }
}

// ---------------- final affine: a = g*(o_acc - s2) + b ----------------
__global__ __launch_bounds__(256) void out_affine_kernel(const float* __restrict__ o_acc,
                                                         const float* __restrict__ s2,
                                                         const float* __restrict__ g,
                                                         const float* __restrict__ bb,
                                                         unsigned short* __restrict__ a_bf) {
    int i = blockIdx.x * 256 + threadIdx.x;
    if (i >= BATCH * NQ * HIDDEN) return;
    int n = i / HIDDEN, d = i - n * HIDDEN;
    a_bf[i] = f2bf(g[d] * (o_acc[i] - s2[n]) + bb[d]);
}

// ---------------- LN over contiguous 768-rows (f32 in-place) ----------------
__global__ __launch_bounds__(256) void ln_f32_rows(float* __restrict__ base,
                                                   const float* __restrict__ g,
                                                   const float* __restrict__ b) {
    int rh = blockIdx.x;
    float* p = base + (size_t)rh * 768;
    int t = threadIdx.x;
    float x0 = p[t], x1 = p[t + 256], x2 = p[t + 512];
    float s = x0 + x1 + x2, s2 = x0 * x0 + x1 * x1 + x2 * x2;
    __shared__ float sm[8];
    block_reduce2_256(s, s2, sm);
    float mu = s * (1.f / 768.f);
    float var = s2 * (1.f / 768.f) - mu * mu;
    float inv = rsqrtf(var + LN_EPS);
    p[t]       = (x0 - mu) * inv * g[t]       + b[t];
    p[t + 256] = (x1 - mu) * inv * g[t + 256] + b[t + 256];
    p[t + 512] = (x2 - mu) * inv * g[t + 512] + b[t + 512];
}

// ---------------- inst attention with fused K/V LayerNorm (raw f32 kv in, bf16 out) ----------------
__global__ __launch_bounds__(256) void attn_inst_kernel(const float* __restrict__ queries,
                                                        const float* __restrict__ kv,   // raw
                                                        const float* __restrict__ g,
                                                        const float* __restrict__ bb,
                                                        unsigned short* __restrict__ qatt) {
    int bidx = blockIdx.x;
    int b = bidx >> 6, n = bidx & 63;
    __shared__ float qg[HIDDEN];
    __shared__ float sc[LI], sc2[LI];
    __shared__ float2 stv[LI];
    __shared__ float sm[8];
    int t = threadIdx.x, lane = t & 63, w = t >> 6;
    const float* q = queries + (size_t)n * HIDDEN;
    float pgs = 0.f, pqb = 0.f;
    for (int d = t; d < HIDDEN; d += 256) {
        float qd = q[d], gg = g[d];
        qg[d] = qd * gg;
        pgs += qd * gg;
        pqb += qd * bb[d];
    }
    block_reduce2_256(pgs, pqb, sm);
    float qgs = pgs, qb = pqb;

    const float* kb = kv + (size_t)b * LI * 1536;
    for (int j = w; j < LI; j += 4) {
        const float* kr = kb + (size_t)j * 1536;
        const float* vr = kr + 768;
        float dotg = 0, sk = 0, s2k = 0, sv = 0, s2v = 0;
        #pragma unroll
        for (int i = 0; i < 12; i++) {
            int d = lane + i * 64;
            float kd = kr[d], vd = vr[d];
            dotg = fmaf(qg[d], kd, dotg);
            sk += kd; s2k = fmaf(kd, kd, s2k);
            sv += vd; s2v = fmaf(vd, vd, s2v);
        }
        #pragma unroll
        for (int o = 32; o; o >>= 1) {
            dotg += __shfl_down(dotg, o); sk += __shfl_down(sk, o); s2k += __shfl_down(s2k, o);
            sv += __shfl_down(sv, o); s2v += __shfl_down(s2v, o);
        }
        if (lane == 0) {
            float muk = sk * (1.f / 768.f);
            float invk = rsqrtf(s2k * (1.f / 768.f) - muk * muk + LN_EPS);
            sc[j] = SCALE_QK * (invk * dotg - muk * invk * qgs + qb);
            float muv = sv * (1.f / 768.f);
            float invv = rsqrtf(s2v * (1.f / 768.f) - muv * muv + LN_EPS);
            stv[j] = make_float2(muv * invv, invv);
        }
    }
    __syncthreads();
    float m = -1e30f;
    for (int j = 0; j < LI; j++) m = fmaxf(m, sc[j]);
    if (t < LI) sc2[t] = expf(sc[t] - m);
    __syncthreads();
    float s = 0;
    for (int j = 0; j < LI; j++) s += sc2[j];
    float invs = 1.f / s;
    float o0 = 0, o1 = 0, o2 = 0, s2sum = 0;
    for (int j = 0; j < LI; j++) {
        float p = sc2[j] * invs;
        float pt = p * stv[j].y;
        s2sum = fmaf(p, stv[j].x, s2sum);
        const float* vr = kb + (size_t)j * 1536 + 768;
        o0 = fmaf(pt, vr[t], o0);
        o1 = fmaf(pt, vr[t + 256], o1);
        o2 = fmaf(pt, vr[t + 512], o2);
    }
    unsigned short* orow = qatt + ((size_t)b * NQ + n) * HIDDEN;
    orow[t]       = f2bf(g[t]       * (o0 - s2sum) + bb[t]);
    orow[t + 256] = f2bf(g[t + 256] * (o1 - s2sum) + bb[t + 256]);
    orow[t + 512] = f2bf(g[t + 512] * (o2 - s2sum) + bb[t + 512]);
}

// ---------------- host launch ----------------
extern "C" void kernel_launch(void* const* d_in, const int* in_sizes, int n_in,
                              void* d_out, int out_size, void* d_ws, size_t ws_size,
                              hipStream_t stream) {
    (void)in_sizes; (void)n_in; (void)out_size; (void)ws_size;
    const float* x_mm    = (const float*)d_in[0];
    const float* instf   = (const float*)d_in[1];
    const float* queries = (const float*)d_in[2];
    const float* W_proj  = (const float*)d_in[3];
    const float* b_proj  = (const float*)d_in[4];
    const float* W_kvi   = (const float*)d_in[5];
    const float* b_kvi   = (const float*)d_in[6];
    const float* W_oi    = (const float*)d_in[7];
    const float* b_oi    = (const float*)d_in[8];
    const float* W_kvm   = (const float*)d_in[9];
    const float* b_kvm   = (const float*)d_in[10];
    const float* W_om    = (const float*)d_in[11];
    const float* b_om    = (const float*)d_in[12];
    const float* ln_g    = (const float*)d_in[13];
    const float* ln_b    = (const float*)d_in[14];
    float* out = (float*)d_out;

    char* ws = (char*)d_ws;
    size_t off = 0;
    auto carve = [&](size_t bytes) -> char* {
        char* p = ws + off;
        off += (bytes + 255) & ~(size_t)255;
        return p;
    };
    unsigned short* x_bf   = (unsigned short*)carve((size_t)BATCH * MSEQ * MMHID * 2);
    unsigned short* wtm_bf = (unsigned short*)carve((size_t)2 * HIDDEN * MMHID * 2);
    unsigned short* kv_mm  = (unsigned short*)carve((size_t)BATCH * MSEQ * 2 * HIDDEN * 2);
    unsigned short* wp_bf  = (unsigned short*)carve((size_t)768 * 768 * 2);
    unsigned short* wkvi_bf= (unsigned short*)carve((size_t)1536 * 768 * 2);
    unsigned short* woi_bf = (unsigned short*)carve((size_t)768 * 768 * 2);
    unsigned short* wom_bf = (unsigned short*)carve((size_t)768 * 768 * 2);
    unsigned short* a1_bf  = (unsigned short*)carve((size_t)384 * 768 * 2);
    unsigned short* inst_bf= (unsigned short*)carve((size_t)384 * 768 * 2);
    float*          kv_inst= (float*)carve((size_t)384 * 1536 * 4);
    unsigned short* qatt_bf= (unsigned short*)carve((size_t)256 * 768 * 2);
    float*          q2     = (float*)carve((size_t)256 * 768 * 4);
    unsigned short* q2bf   = (unsigned short*)carve((size_t)BATCH * 128 * 768 * 2);
    float*          scores = (float*)carve((size_t)BATCH * 64 * MSEQ * 4);
    unsigned short* P_abs  = (unsigned short*)carve((size_t)BATCH * 64 * MSEQ * 2);
    float*          o_acc  = (float*)carve((size_t)BATCH * 64 * 768 * 4);
    unsigned short* a_bf   = (unsigned short*)carve((size_t)256 * 768 * 2);
    float2*         stats  = (float2*)carve((size_t)BATCH * MSEQ * 2 * sizeof(float2));
    float2*         stat_s = (float2*)carve((size_t)6 * GM * sizeof(float2));
    float*          qgsum  = (float*)carve((size_t)256 * 4);
    float*          s2     = (float*)carve((size_t)256 * 4);

    // ---- prep: 5 weight transposes + instf cvt (z=5) + x cvt (z=6,7 grid-stride), single dispatch ----
    PrepJobs tw;
    tw.W[0] = W_kvm;  tw.Wt[0] = wtm_bf;  tw.D[0] = 1024; tw.C[0] = 1536;
    tw.W[1] = W_proj; tw.Wt[1] = wp_bf;   tw.D[1] = 768;  tw.C[1] = 768;
    tw.W[2] = W_kvi;  tw.Wt[2] = wkvi_bf; tw.D[2] = 768;  tw.C[2] = 1536;
    tw.W[3] = W_oi;   tw.Wt[3] = woi_bf;  tw.D[3] = 768;  tw.C[3] = 768;
    tw.W[4] = W_om;   tw.Wt[4] = wom_bf;  tw.D[4] = 768;  tw.C[4] = 768;
    tw.inst_in = instf; tw.inst_out = a1_bf;
    tw.n8_valid = BATCH * LI * 768 / 8; tw.n8_total = 384 * 768 / 8;
    tw.x_in = x_mm; tw.x_out = x_bf; tw.n8x = BATCH * MSEQ * MMHID / 8;
    prep_kernel<<<dim3(48, 32, 8), 256, 0, stream>>>(tw);

    // ---- mm branch: 256^2 double-buffered GEMM + coalesced stat partials -> stats_fin ----
    hipError_t attr_ok = hipFuncSetAttribute((const void*)gemm_kv256_kernel,
                                             hipFuncAttributeMaxDynamicSharedMemorySize, 131072);
    if (attr_ok == hipSuccess) {
        gemm_kv256_kernel<<<(GM / 256) * (GN / 256), 512, 131072, stream>>>(x_bf, wtm_bf, b_kvm, kv_mm, stat_s);
        stats_fin_kernel<<<(BATCH * MSEQ * 2 + 255) / 256, 256, 0, stream>>>(stat_s, stats, BATCH * MSEQ * 2);
    } else {
        gemm_kv128_kernel<<<(GM / 128) * (GN / 128), 256, 0, stream>>>(x_bf, wtm_bf, b_kvm, kv_mm);
        stats_kernel<<<BATCH * MSEQ * 2, 256, 0, stream>>>(kv_mm, stats);
    }

    // ---- inst branch (bf16 MFMA; LN of kv_inst folded into attn) ----
    gemm_tile_kernel<768, true><<<dim3(3, 6), 256, 0, stream>>>(a1_bf, wp_bf, b_proj, inst_bf, 768);
    gemm_tile_kernel<768, false><<<dim3(3, 12), 256, 0, stream>>>(inst_bf, wkvi_bf, b_kvi, kv_inst, 1536);
    attn_inst_kernel<<<BATCH * NQ, 256, 0, stream>>>(queries, kv_inst, ln_g, ln_b, qatt_bf);
    gemm_tile_kernel<768, false><<<dim3(2, 6), 256, 0, stream>>>(qatt_bf, woi_bf, b_oi, q2, 768);

    // ---- windowed attention ----
    cvt_q_kernel<<<BATCH * 128, 256, 0, stream>>>(q2, ln_g, ln_b, q2bf, qgsum);
    gemm_scores_kernel<<<dim3(MSEQ / 128, BATCH), 256, 0, stream>>>(q2bf, kv_mm, scores);
    win_softmax_kernel<<<BATCH * NQ, 512, 0, stream>>>(scores, stats, qgsum, P_abs, s2, o_acc);
    pv_chunk_kernel<<<dim3(MSEQ / 64, BATCH), 768, 0, stream>>>(P_abs, kv_mm, o_acc);
    out_affine_kernel<<<(BATCH * NQ * HIDDEN + 255) / 256, 256, 0, stream>>>(o_acc, s2, ln_g, ln_b, a_bf);

    // ---- output projection ----
    gemm_tile_kernel<768, false><<<dim3(2, 6), 256, 0, stream>>>(a_bf, wom_bf, b_om, out, 768);
    ln_f32_rows<<<BATCH * NQ, 256, 0, stream>>>(out, ln_g, ln_b);
}

// Round 17
// 301.518 us; speedup vs baseline: 1.0036x; 1.0033x over previous
//
#include <hip/hip_runtime.h>

#define HIDDEN 768
#define NQ 64
#define WINSZ 512
#define MSEQ 8192
#define BATCH 4
#define LI 77
#define MMHID 1024
#define LN_EPS 1e-5f
#define SCALE_QK 0.03608439182435161f  // 1/sqrt(768)

typedef __attribute__((ext_vector_type(8))) short short8v;
typedef __attribute__((ext_vector_type(4))) float f32x4;
typedef __attribute__((ext_vector_type(8))) unsigned short u16x8;

#define AS1 __attribute__((address_space(1)))
#define AS3 __attribute__((address_space(3)))

__device__ inline unsigned short f2bf(float f) {
    unsigned u = __float_as_uint(f);
    u += 0x7fffu + ((u >> 16) & 1u);
    return (unsigned short)(u >> 16);
}
__device__ inline float bf2f(unsigned short h) {
    return __uint_as_float(((unsigned)h) << 16);
}

// ---------------- block reduce (256 threads, 4 waves) ----------------
__device__ inline void block_reduce2_256(float& s1, float& s2, float* sm) {
    #pragma unroll
    for (int o = 32; o; o >>= 1) { s1 += __shfl_down(s1, o); s2 += __shfl_down(s2, o); }
    int lane = threadIdx.x & 63, w = threadIdx.x >> 6;
    __syncthreads();
    if (lane == 0) { sm[w] = s1; sm[4 + w] = s2; }
    __syncthreads();
    s1 = sm[0] + sm[1] + sm[2] + sm[3];
    s2 = sm[4] + sm[5] + sm[6] + sm[7];
}

// ---- q2 f32 (pre-LN) -> LN -> q2bf bf16 (4x128x768) with g*SCALE folded; qgsum per row ----
__global__ __launch_bounds__(256) void cvt_q_kernel(const float* __restrict__ q2,
                                                    const float* __restrict__ g,
                                                    const float* __restrict__ bb,
                                                    unsigned short* __restrict__ q2bf,
                                                    float* __restrict__ qgsum) {
    int blk = blockIdx.x;               // b*128 + r
    int b = blk >> 7, r = blk & 127;
    int t = threadIdx.x;
    __shared__ float sm[8];
    unsigned short* orow = q2bf + (size_t)blk * HIDDEN;
    if (r >= 64) {
        orow[t] = 0; orow[t + 256] = 0; orow[t + 512] = 0;
        return;
    }
    const float* qrow = q2 + ((size_t)(b * 64 + r)) * HIDDEN;
    float y0 = qrow[t], y1 = qrow[t + 256], y2 = qrow[t + 512];
    float s = y0 + y1 + y2, s2 = y0 * y0 + y1 * y1 + y2 * y2;
    block_reduce2_256(s, s2, sm);
    float mu = s * (1.f / 768.f);
    float var = s2 * (1.f / 768.f) - mu * mu;
    float inv = rsqrtf(var + LN_EPS);
    float qw0 = (y0 - mu) * inv * g[t]       + bb[t];
    float qw1 = (y1 - mu) * inv * g[t + 256] + bb[t + 256];
    float qw2 = (y2 - mu) * inv * g[t + 512] + bb[t + 512];
    float v0 = qw0 * g[t]       * SCALE_QK;
    float v1 = qw1 * g[t + 256] * SCALE_QK;
    float v2 = qw2 * g[t + 512] * SCALE_QK;
    orow[t] = f2bf(v0); orow[t + 256] = f2bf(v1); orow[t + 512] = f2bf(v2);
    float qs = v0 + v1 + v2, dummy = 0.f;
    block_reduce2_256(qs, dummy, sm);
    if (t == 0) qgsum[b * 64 + r] = qs;
}

// ---------------- prep kernel: 5 weight transposes + instf cvt (z=5) + x cvt (z=6,7 grid-stride) ----------------
struct PrepJobs {
    const float* W[5];
    unsigned short* Wt[5];
    int D[5];
    int C[5];
    const float* inst_in;
    unsigned short* inst_out;
    int n8_valid;
    int n8_total;
    const float* x_in;
    unsigned short* x_out;
    int n8x;
};
__global__ __launch_bounds__(256) void prep_kernel(PrepJobs tw) {
    int z = blockIdx.z;
    if (z >= 6) {
        int per_slice = (int)(gridDim.x * gridDim.y);
        int flat = blockIdx.y * gridDim.x + blockIdx.x;
        int i0 = ((z - 6) * per_slice + flat) * 256 + threadIdx.x;
        int stride = 2 * per_slice * 256;
        for (int i = i0; i < tw.n8x; i += stride) {
            const float4* p = (const float4*)(tw.x_in + (size_t)i * 8);
            float4 a = p[0], b = p[1];
            u16x8 o;
            o[0] = f2bf(a.x); o[1] = f2bf(a.y); o[2] = f2bf(a.z); o[3] = f2bf(a.w);
            o[4] = f2bf(b.x); o[5] = f2bf(b.y); o[6] = f2bf(b.z); o[7] = f2bf(b.w);
            *(u16x8*)(tw.x_out + (size_t)i * 8) = o;
        }
        return;
    }
    if (z == 5) {
        int flat = blockIdx.y * gridDim.x + blockIdx.x;
        int i = flat * 256 + threadIdx.x;
        if (i >= tw.n8_total) return;
        u16x8 o = {};
        if (i < tw.n8_valid) {
            const float4* p = (const float4*)(tw.inst_in + (size_t)i * 8);
            float4 a = p[0], b = p[1];
            o[0] = f2bf(a.x); o[1] = f2bf(a.y); o[2] = f2bf(a.z); o[3] = f2bf(a.w);
            o[4] = f2bf(b.x); o[5] = f2bf(b.y); o[6] = f2bf(b.z); o[7] = f2bf(b.w);
        }
        *(u16x8*)(tw.inst_out + (size_t)i * 8) = o;
        return;
    }
    int C = tw.C[z], D = tw.D[z];
    int n0 = blockIdx.x * 32, k0 = blockIdx.y * 32;
    if (n0 >= C || k0 >= D) return;
    const float* W = tw.W[z];
    unsigned short* Wt = tw.Wt[z];
    __shared__ float tile[32][33];
    int tx = threadIdx.x & 31, ty = (threadIdx.x >> 5);  // 32x8
    #pragma unroll
    for (int i = 0; i < 32; i += 8)
        tile[ty + i][tx] = W[(size_t)(k0 + ty + i) * C + n0 + tx];
    __syncthreads();
    #pragma unroll
    for (int i = 0; i < 32; i += 8)
        Wt[(size_t)(n0 + ty + i) * D + k0 + tx] = f2bf(tile[tx][ty + i]);
}

#define GM 32768
#define GN 1536
#define GK 1024

// ---------------- big GEMM: 256x256 tile, 8 waves, double-buffered 128KB LDS (R12-verified) ----------------
__global__ __launch_bounds__(512, 2) void gemm_kv256_kernel(const unsigned short* __restrict__ A,
                                                            const unsigned short* __restrict__ Bt,
                                                            const float* __restrict__ bias,
                                                            unsigned short* __restrict__ C) {
    extern __shared__ char smem[];
    unsigned short* sA = (unsigned short*)smem;            // [2][256*64]
    unsigned short* sB = (unsigned short*)(smem + 65536);  // [2][256*64]

    int nwg = gridDim.x;                                   // 768
    int bid = blockIdx.x;
    int wg = bid;
    if ((nwg & 7) == 0) { int cpx = nwg >> 3; wg = (bid & 7) * cpx + (bid >> 3); }
    int bm = wg / (GN / 256), bn = wg % (GN / 256);
    int row0 = bm * 256, col0 = bn * 256;

    int tid = threadIdx.x;
    int lane = tid & 63, wid = tid >> 6;
    int wm = wid >> 2, wn = wid & 3;                       // 2M x 4N

    f32x4 acc[8][4] = {};

    int rS[4], cS[4];
    #pragma unroll
    for (int i = 0; i < 4; i++) {
        int ch = wid * 4 + i;
        int r = ch * 8 + (lane >> 3);
        rS[i] = r;
        cS[i] = ((lane & 7) ^ (r & 7)) << 3;
    }

    auto STAGE = [&](int k0, int pbuf) {
        unsigned short* dA = sA + pbuf * 16384;
        unsigned short* dB = sB + pbuf * 16384;
        #pragma unroll
        for (int i = 0; i < 4; i++) {
            int ch = wid * 4 + i;
            const unsigned short* ga = A + (size_t)(row0 + rS[i]) * GK + k0 + cS[i];
            __builtin_amdgcn_global_load_lds((const AS1 unsigned int*)ga,
                                             (AS3 unsigned int*)&dA[ch * 512], 16, 0, 0);
            const unsigned short* gb = Bt + (size_t)(col0 + rS[i]) * GK + k0 + cS[i];
            __builtin_amdgcn_global_load_lds((const AS1 unsigned int*)gb,
                                             (AS3 unsigned int*)&dB[ch * 512], 16, 0, 0);
        }
    };

    STAGE(0, 0);
    __syncthreads();

    for (int kt = 0; kt < GK / 64; kt++) {
        int cur = kt & 1;
        if (kt < GK / 64 - 1) STAGE((kt + 1) * 64, cur ^ 1);

        const char* lA = (const char*)(sA + cur * 16384);
        const char* lB = (const char*)(sB + cur * 16384);

        short8v bfr[4][2];
        #pragma unroll
        for (int n = 0; n < 4; n++)
            #pragma unroll
            for (int kk = 0; kk < 2; kk++) {
                int r = wn * 64 + n * 16 + (lane & 15);
                int ko = (kk * 32 + ((lane >> 4) << 3)) * 2;
                bfr[n][kk] = *(const short8v*)(lB + r * 128 + (ko ^ ((r & 7) << 4)));
            }
        #pragma unroll
        for (int p = 0; p < 4; p++) {
            short8v afr[2][2];
            #pragma unroll
            for (int mf = 0; mf < 2; mf++)
                #pragma unroll
                for (int kk = 0; kk < 2; kk++) {
                    int r = wm * 128 + (p * 2 + mf) * 16 + (lane & 15);
                    int ko = (kk * 32 + ((lane >> 4) << 3)) * 2;
                    afr[mf][kk] = *(const short8v*)(lA + r * 128 + (ko ^ ((r & 7) << 4)));
                }
            __builtin_amdgcn_s_setprio(1);
            #pragma unroll
            for (int mf = 0; mf < 2; mf++)
                #pragma unroll
                for (int n = 0; n < 4; n++)
                    #pragma unroll
                    for (int kk = 0; kk < 2; kk++)
                        acc[p * 2 + mf][n] = __builtin_amdgcn_mfma_f32_16x16x32_bf16(
                            afr[mf][kk], bfr[n][kk], acc[p * 2 + mf][n], 0, 0, 0);
            __builtin_amdgcn_s_setprio(0);
        }
        __syncthreads();
    }

    int crow = (lane >> 4) * 4;
    int ccol = lane & 15;
    #pragma unroll
    for (int m = 0; m < 8; m++) {
        #pragma unroll
        for (int n = 0; n < 4; n++) {
            int gc = col0 + wn * 64 + n * 16 + ccol;
            float bv = bias[gc];
            #pragma unroll
            for (int j = 0; j < 4; j++) {
                int gr = row0 + wm * 128 + m * 16 + crow + j;
                C[(size_t)gr * GN + gc] = f2bf(acc[m][n][j] + bv);
            }
        }
    }
}

// ---------------- fallback: 128x128 GEMM (R8-verified) ----------------
__global__ __launch_bounds__(256) void gemm_kv128_kernel(const unsigned short* __restrict__ A,
                                                         const unsigned short* __restrict__ Bt,
                                                         const float* __restrict__ bias,
                                                         unsigned short* __restrict__ C) {
    __shared__ unsigned short sA[128 * 64];
    __shared__ unsigned short sB[128 * 64];

    int nwg = gridDim.x;
    int bid = blockIdx.x;
    int wg = bid;
    if ((nwg & 7) == 0) { int cpx = nwg >> 3; wg = (bid & 7) * cpx + (bid >> 3); }
    int bm = wg / (GN / 128), bn = wg % (GN / 128);
    int row0 = bm * 128, col0 = bn * 128;

    int tid = threadIdx.x;
    int lane = tid & 63, wid = tid >> 6;
    int wr = wid >> 1, wc = wid & 1;

    f32x4 acc[4][4] = {};

    int rS[4], cS[4];
    #pragma unroll
    for (int i = 0; i < 4; i++) {
        int ch = wid * 4 + i;
        int r = ch * 8 + (lane >> 3);
        rS[i] = r;
        cS[i] = ((lane & 7) ^ (r & 7)) << 3;
    }

    for (int k0 = 0; k0 < GK; k0 += 64) {
        #pragma unroll
        for (int i = 0; i < 4; i++) {
            int ch = wid * 4 + i;
            const unsigned short* ga = A + (size_t)(row0 + rS[i]) * GK + k0 + cS[i];
            __builtin_amdgcn_global_load_lds((const AS1 unsigned int*)ga,
                                             (AS3 unsigned int*)&sA[ch * 512], 16, 0, 0);
            const unsigned short* gb = Bt + (size_t)(col0 + rS[i]) * GK + k0 + cS[i];
            __builtin_amdgcn_global_load_lds((const AS1 unsigned int*)gb,
                                             (AS3 unsigned int*)&sB[ch * 512], 16, 0, 0);
        }
        __syncthreads();

        #pragma unroll
        for (int kk = 0; kk < 64; kk += 32) {
            int ko = (kk + ((lane >> 4) << 3)) * 2;
            short8v af[4], bf[4];
            #pragma unroll
            for (int m = 0; m < 4; m++) {
                int r = wr * 64 + m * 16 + (lane & 15);
                int addr = r * 128 + (ko ^ ((r & 7) << 4));
                af[m] = *(const short8v*)((const char*)sA + addr);
            }
            #pragma unroll
            for (int n = 0; n < 4; n++) {
                int r = wc * 64 + n * 16 + (lane & 15);
                int addr = r * 128 + (ko ^ ((r & 7) << 4));
                bf[n] = *(const short8v*)((const char*)sB + addr);
            }
            #pragma unroll
            for (int m = 0; m < 4; m++)
                #pragma unroll
                for (int n = 0; n < 4; n++)
                    acc[m][n] = __builtin_amdgcn_mfma_f32_16x16x32_bf16(af[m], bf[n], acc[m][n], 0, 0, 0);
        }
        __syncthreads();
    }

    int crow = (lane >> 4) * 4;
    int ccol = lane & 15;
    #pragma unroll
    for (int m = 0; m < 4; m++) {
        #pragma unroll
        for (int n = 0; n < 4; n++) {
            int gc = col0 + wc * 64 + n * 16 + ccol;
            float bv = bias[gc];
            #pragma unroll
            for (int j = 0; j < 4; j++) {
                int gr = row0 + wr * 64 + m * 16 + crow + j;
                C[(size_t)gr * GN + gc] = f2bf(acc[m][n][j] + bv);
            }
        }
    }
}

// ---------------- LN stats, wave-per-row-half, u16x8-vectorized, grid-strided ----------------
// Each 64-lane wave owns one 768-elem row-half: lane reads chunk lane (16B) and,
// for lane<32, chunk 64+lane. Shuffle-reduce, lane 0 stores {mu*inv, inv}.
__global__ __launch_bounds__(256) void stats_kernel(const unsigned short* __restrict__ kv,
                                                    float2* __restrict__ stats, int nrh) {
    int wglob = blockIdx.x * 4 + (threadIdx.x >> 6);
    int lane = threadIdx.x & 63;
    int nw = gridDim.x * 4;
    for (int rh = wglob; rh < nrh; rh += nw) {
        const unsigned short* p = kv + (size_t)rh * 768;
        float s = 0.f, q = 0.f;
        u16x8 v = *(const u16x8*)(p + lane * 8);
        #pragma unroll
        for (int j = 0; j < 8; j++) { float f = bf2f(v[j]); s += f; q = fmaf(f, f, q); }
        if (lane < 32) {
            u16x8 v2 = *(const u16x8*)(p + 512 + lane * 8);
            #pragma unroll
            for (int j = 0; j < 8; j++) { float f = bf2f(v2[j]); s += f; q = fmaf(f, f, q); }
        }
        #pragma unroll
        for (int o = 32; o; o >>= 1) { s += __shfl_down(s, o); q += __shfl_down(q, o); }
        if (lane == 0) {
            float mu = s * (1.f / 768.f);
            float var = q * (1.f / 768.f) - mu * mu;
            float inv = rsqrtf(var + LN_EPS);
            stats[rh] = make_float2(mu * inv, inv);
        }
    }
}

// ---------------- generic small MFMA GEMM: A(Mp x TK)bf16 @ Bt(N x TK)^T + bias ----------------
template <int TK, bool OUT_BF16>
__global__ __launch_bounds__(256) void gemm_tile_kernel(const unsigned short* __restrict__ A,
                                                        const unsigned short* __restrict__ Bt,
                                                        const float* __restrict__ bias,
                                                        void* __restrict__ Cout, int N) {
    __shared__ unsigned short sA[128 * 64];
    __shared__ unsigned short sB[128 * 64];

    int row0 = blockIdx.x * 128, col0 = blockIdx.y * 128;
    int tid = threadIdx.x;
    int lane = tid & 63, wid = tid >> 6;
    int wr = wid >> 1, wc = wid & 1;

    f32x4 acc[4][4] = {};

    int rS[4], cS[4];
    #pragma unroll
    for (int i = 0; i < 4; i++) {
        int ch = wid * 4 + i;
        int r = ch * 8 + (lane >> 3);
        rS[i] = r;
        cS[i] = ((lane & 7) ^ (r & 7)) << 3;
    }

    for (int k0 = 0; k0 < TK; k0 += 64) {
        #pragma unroll
        for (int i = 0; i < 4; i++) {
            int ch = wid * 4 + i;
            const unsigned short* ga = A + (size_t)(row0 + rS[i]) * TK + k0 + cS[i];
            __builtin_amdgcn_global_load_lds((const AS1 unsigned int*)ga,
                                             (AS3 unsigned int*)&sA[ch * 512], 16, 0, 0);
            const unsigned short* gb = Bt + (size_t)(col0 + rS[i]) * TK + k0 + cS[i];
            __builtin_amdgcn_global_load_lds((const AS1 unsigned int*)gb,
                                             (AS3 unsigned int*)&sB[ch * 512], 16, 0, 0);
        }
        __syncthreads();

        #pragma unroll
        for (int kk = 0; kk < 64; kk += 32) {
            int ko = (kk + ((lane >> 4) << 3)) * 2;
            short8v af[4], bf[4];
            #pragma unroll
            for (int m = 0; m < 4; m++) {
                int r = wr * 64 + m * 16 + (lane & 15);
                int addr = r * 128 + (ko ^ ((r & 7) << 4));
                af[m] = *(const short8v*)((const char*)sA + addr);
            }
            #pragma unroll
            for (int n = 0; n < 4; n++) {
                int r = wc * 64 + n * 16 + (lane & 15);
                int addr = r * 128 + (ko ^ ((r & 7) << 4));
                bf[n] = *(const short8v*)((const char*)sB + addr);
            }
            #pragma unroll
            for (int m = 0; m < 4; m++)
                #pragma unroll
                for (int n = 0; n < 4; n++)
                    acc[m][n] = __builtin_amdgcn_mfma_f32_16x16x32_bf16(af[m], bf[n], acc[m][n], 0, 0, 0);
        }
        __syncthreads();
    }

    int crow = (lane >> 4) * 4;
    int ccol = lane & 15;
    #pragma unroll
    for (int m = 0; m < 4; m++) {
        #pragma unroll
        for (int n = 0; n < 4; n++) {
            int gc = col0 + wc * 64 + n * 16 + ccol;
            float bv = bias[gc];
            #pragma unroll
            for (int j = 0; j < 4; j++) {
                int gr = row0 + wr * 64 + m * 16 + crow + j;
                float v = acc[m][n][j] + bv;
                if (OUT_BF16) ((unsigned short*)Cout)[(size_t)gr * N + gc] = f2bf(v);
                else          ((float*)Cout)[(size_t)gr * N + gc] = v;
            }
        }
    }
}

// ---------------- scores GEMM: q2bf[b](128x768) @ K_b^T (raw) -> S0 f32 (64x8192 per b) ----------------
__global__ __launch_bounds__(256) void gemm_scores_kernel(const unsigned short* __restrict__ Aall,
                                                          const unsigned short* __restrict__ kv,
                                                          float* __restrict__ scores) {
    __shared__ unsigned short sA[128 * 64];
    __shared__ unsigned short sB[128 * 64];

    int b = blockIdx.y;
    int col0 = blockIdx.x * 128;
    const unsigned short* A = Aall + (size_t)b * 128 * HIDDEN;
    const unsigned short* Bt = kv + (size_t)b * MSEQ * 1536;

    int tid = threadIdx.x;
    int lane = tid & 63, wid = tid >> 6;
    int wr = wid >> 1, wc = wid & 1;

    f32x4 acc[4][4] = {};

    int rS[4], cS[4];
    #pragma unroll
    for (int i = 0; i < 4; i++) {
        int ch = wid * 4 + i;
        int r = ch * 8 + (lane >> 3);
        rS[i] = r;
        cS[i] = ((lane & 7) ^ (r & 7)) << 3;
    }

    for (int k0 = 0; k0 < HIDDEN; k0 += 64) {
        #pragma unroll
        for (int i = 0; i < 4; i++) {
            int ch = wid * 4 + i;
            const unsigned short* ga = A + (size_t)rS[i] * HIDDEN + k0 + cS[i];
            __builtin_amdgcn_global_load_lds((const AS1 unsigned int*)ga,
                                             (AS3 unsigned int*)&sA[ch * 512], 16, 0, 0);
            const unsigned short* gb = Bt + (size_t)(col0 + rS[i]) * 1536 + k0 + cS[i];
            __builtin_amdgcn_global_load_lds((const AS1 unsigned int*)gb,
                                             (AS3 unsigned int*)&sB[ch * 512], 16, 0, 0);
        }
        __syncthreads();

        #pragma unroll
        for (int kk = 0; kk < 64; kk += 32) {
            int ko = (kk + ((lane >> 4) << 3)) * 2;
            short8v af[4], bf[4];
            #pragma unroll
            for (int m = 0; m < 4; m++) {
                int r = wr * 64 + m * 16 + (lane & 15);
                int addr = r * 128 + (ko ^ ((r & 7) << 4));
                af[m] = *(const short8v*)((const char*)sA + addr);
            }
            #pragma unroll
            for (int n = 0; n < 4; n++) {
                int r = wc * 64 + n * 16 + (lane & 15);
                int addr = r * 128 + (ko ^ ((r & 7) << 4));
                bf[n] = *(const short8v*)((const char*)sB + addr);
            }
            #pragma unroll
            for (int m = 0; m < 4; m++)
                #pragma unroll
                for (int n = 0; n < 4; n++)
                    acc[m][n] = __builtin_amdgcn_mfma_f32_16x16x32_bf16(af[m], bf[n], acc[m][n], 0, 0, 0);
        }
        __syncthreads();
    }

    int crow = (lane >> 4) * 4;
    int ccol = lane & 15;
    #pragma unroll
    for (int m = 0; m < 4; m++) {
        #pragma unroll
        for (int n = 0; n < 4; n++) {
            int gc = col0 + wc * 64 + n * 16 + ccol;
            #pragma unroll
            for (int j = 0; j < 4; j++) {
                int gr = wr * 64 + m * 16 + crow + j;
                if (gr < 64)
                    scores[((size_t)(b * 64 + gr)) * MSEQ + gc] = acc[m][n][j];
            }
        }
    }
}

// ---------------- windowed softmax with LN-fold; also zeros o_acc row ----------------
__global__ __launch_bounds__(512) void win_softmax_kernel(const float* __restrict__ scores,
                                                          const float2* __restrict__ stats,
                                                          const float* __restrict__ qgsum,
                                                          unsigned short* __restrict__ P_abs,
                                                          float* __restrict__ s2out,
                                                          float* __restrict__ o_acc) {
    int bidx = blockIdx.x;
    int b = bidx >> 6, n = bidx & 63;
    int step = (MSEQ - WINSZ) / (NQ - 1);
    int s = n * step;
    if (s + WINSZ > MSEQ) s = MSEQ - WINSZ;

    __shared__ float sm[8];
    int t = threadIdx.x, lane = t & 63, w = t >> 6;

    float* oz = o_acc + ((size_t)(b * 64 + n)) * HIDDEN;
    oz[t] = 0.f;
    if (t < 256) oz[512 + t] = 0.f;

    int r_abs = s + t;
    size_t rowidx = (size_t)b * MSEQ + r_abs;
    float2 stk = stats[rowidx * 2 + 0];
    float qg = qgsum[b * 64 + n];
    float a = stk.y * scores[((size_t)(b * 64 + n)) * MSEQ + r_abs] - qg * stk.x;

    float m = a;
    #pragma unroll
    for (int o = 32; o; o >>= 1) m = fmaxf(m, __shfl_down(m, o));
    if (lane == 0) sm[w] = m;
    __syncthreads();
    m = sm[0];
    #pragma unroll
    for (int i = 1; i < 8; i++) m = fmaxf(m, sm[i]);
    float e = expf(a - m);
    float ssum = e;
    #pragma unroll
    for (int o = 32; o; o >>= 1) ssum += __shfl_down(ssum, o);
    __syncthreads();
    if (lane == 0) sm[w] = ssum;
    __syncthreads();
    ssum = 0;
    #pragma unroll
    for (int i = 0; i < 8; i++) ssum += sm[i];
    float p = e / ssum;

    float2 stv = stats[rowidx * 2 + 1];
    float pt = p * stv.y;
    float s2p = p * stv.x;
    #pragma unroll
    for (int o = 32; o; o >>= 1) s2p += __shfl_down(s2p, o);
    __syncthreads();
    if (lane == 0) sm[w] = s2p;
    __syncthreads();
    if (t == 0) {
        float s2 = 0;
        #pragma unroll
        for (int i = 0; i < 8; i++) s2 += sm[i];
        s2out[b * 64 + n] = s2;
    }

    unsigned short* prow = P_abs + ((size_t)(b * 64 + n)) * MSEQ;
    for (int pos = t; pos < MSEQ; pos += 512)
        if (pos < s || pos >= s + WINSZ) prow[pos] = 0;
    prow[r_abs] = f2bf(pt);
}

// ---------------- PV chunks ----------------
__global__ __launch_bounds__(768) void pv_chunk_kernel(const unsigned short* __restrict__ P_abs,
                                                       const unsigned short* __restrict__ kv,
                                                       float* __restrict__ out_acc) {
    int b = blockIdx.y;
    int r0 = blockIdx.x * 64;
    int t = threadIdx.x;

    int n_lo = (r0 >= 512) ? ((r0 - 512) / 121 + 1) : 0;
    int n_hi = (r0 + 63) / 121;
    if (n_hi > 63) n_hi = 63;

    __shared__ float pw[5][64];
    if (t < 5 * 64) {
        int ni = t >> 6, r = t & 63;
        int n = n_lo + ni;
        float v = 0.f;
        if (n <= n_hi)
            v = bf2f(P_abs[((size_t)(b * 64 + n)) * MSEQ + r0 + r]);
        pw[ni][r] = v;
    }
    __syncthreads();

    const unsigned short* vbase = kv + ((size_t)(b * MSEQ + r0)) * 1536 + 768;
    float acc[5] = {};
    #pragma unroll 8
    for (int r = 0; r < 64; ++r) {
        float v = bf2f(vbase[(size_t)r * 1536 + t]);
        #pragma unroll
        for (int ni = 0; ni < 5; ni++) acc[ni] = fmaf(v, pw[ni][r], acc[ni]);
    }
    #pragma unroll
    for (int ni = 0; ni < 5; ni++) {
        int n = n_lo + ni;
        if (n <= n_hi)
            atomicAdd(&out_acc[((size_t)(b * 64 + n)) * HIDDEN + t], acc[ni]);
    }
}

// ---------------- final affine: a = g*(o_acc - s2) + b ----------------
__global__ __launch_bounds__(256) void out_affine_kernel(const float* __restrict__ o_acc,
                                                         const float* __restrict__ s2,
                                                         const float* __restrict__ g,
                                                         const float* __restrict__ bb,
                                                         unsigned short* __restrict__ a_bf) {
    int i = blockIdx.x * 256 + threadIdx.x;
    if (i >= BATCH * NQ * HIDDEN) return;
    int n = i / HIDDEN, d = i - n * HIDDEN;
    a_bf[i] = f2bf(g[d] * (o_acc[i] - s2[n]) + bb[d]);
}

// ---------------- LN over contiguous 768-rows (f32 in-place) ----------------
__global__ __launch_bounds__(256) void ln_f32_rows(float* __restrict__ base,
                                                   const float* __restrict__ g,
                                                   const float* __restrict__ b) {
    int rh = blockIdx.x;
    float* p = base + (size_t)rh * 768;
    int t = threadIdx.x;
    float x0 = p[t], x1 = p[t + 256], x2 = p[t + 512];
    float s = x0 + x1 + x2, s2 = x0 * x0 + x1 * x1 + x2 * x2;
    __shared__ float sm[8];
    block_reduce2_256(s, s2, sm);
    float mu = s * (1.f / 768.f);
    float var = s2 * (1.f / 768.f) - mu * mu;
    float inv = rsqrtf(var + LN_EPS);
    p[t]       = (x0 - mu) * inv * g[t]       + b[t];
    p[t + 256] = (x1 - mu) * inv * g[t + 256] + b[t + 256];
    p[t + 512] = (x2 - mu) * inv * g[t + 512] + b[t + 512];
}

// ---------------- inst attention with fused K/V LayerNorm (raw f32 kv in, bf16 out) ----------------
__global__ __launch_bounds__(256) void attn_inst_kernel(const float* __restrict__ queries,
                                                        const float* __restrict__ kv,   // raw
                                                        const float* __restrict__ g,
                                                        const float* __restrict__ bb,
                                                        unsigned short* __restrict__ qatt) {
    int bidx = blockIdx.x;
    int b = bidx >> 6, n = bidx & 63;
    __shared__ float qg[HIDDEN];
    __shared__ float sc[LI], sc2[LI];
    __shared__ float2 stv[LI];
    __shared__ float sm[8];
    int t = threadIdx.x, lane = t & 63, w = t >> 6;
    const float* q = queries + (size_t)n * HIDDEN;
    float pgs = 0.f, pqb = 0.f;
    for (int d = t; d < HIDDEN; d += 256) {
        float qd = q[d], gg = g[d];
        qg[d] = qd * gg;
        pgs += qd * gg;
        pqb += qd * bb[d];
    }
    block_reduce2_256(pgs, pqb, sm);
    float qgs = pgs, qb = pqb;

    const float* kb = kv + (size_t)b * LI * 1536;
    for (int j = w; j < LI; j += 4) {
        const float* kr = kb + (size_t)j * 1536;
        const float* vr = kr + 768;
        float dotg = 0, sk = 0, s2k = 0, sv = 0, s2v = 0;
        #pragma unroll
        for (int i = 0; i < 12; i++) {
            int d = lane + i * 64;
            float kd = kr[d], vd = vr[d];
            dotg = fmaf(qg[d], kd, dotg);
            sk += kd; s2k = fmaf(kd, kd, s2k);
            sv += vd; s2v = fmaf(vd, vd, s2v);
        }
        #pragma unroll
        for (int o = 32; o; o >>= 1) {
            dotg += __shfl_down(dotg, o); sk += __shfl_down(sk, o); s2k += __shfl_down(s2k, o);
            sv += __shfl_down(sv, o); s2v += __shfl_down(s2v, o);
        }
        if (lane == 0) {
            float muk = sk * (1.f / 768.f);
            float invk = rsqrtf(s2k * (1.f / 768.f) - muk * muk + LN_EPS);
            sc[j] = SCALE_QK * (invk * dotg - muk * invk * qgs + qb);
            float muv = sv * (1.f / 768.f);
            float invv = rsqrtf(s2v * (1.f / 768.f) - muv * muv + LN_EPS);
            stv[j] = make_float2(muv * invv, invv);
        }
    }
    __syncthreads();
    float m = -1e30f;
    for (int j = 0; j < LI; j++) m = fmaxf(m, sc[j]);
    if (t < LI) sc2[t] = expf(sc[t] - m);
    __syncthreads();
    float s = 0;
    for (int j = 0; j < LI; j++) s += sc2[j];
    float invs = 1.f / s;
    float o0 = 0, o1 = 0, o2 = 0, s2sum = 0;
    for (int j = 0; j < LI; j++) {
        float p = sc2[j] * invs;
        float pt = p * stv[j].y;
        s2sum = fmaf(p, stv[j].x, s2sum);
        const float* vr = kb + (size_t)j * 1536 + 768;
        o0 = fmaf(pt, vr[t], o0);
        o1 = fmaf(pt, vr[t + 256], o1);
        o2 = fmaf(pt, vr[t + 512], o2);
    }
    unsigned short* orow = qatt + ((size_t)b * NQ + n) * HIDDEN;
    orow[t]       = f2bf(g[t]       * (o0 - s2sum) + bb[t]);
    orow[t + 256] = f2bf(g[t + 256] * (o1 - s2sum) + bb[t + 256]);
    orow[t + 512] = f2bf(g[t + 512] * (o2 - s2sum) + bb[t + 512]);
}

// ---------------- host launch ----------------
extern "C" void kernel_launch(void* const* d_in, const int* in_sizes, int n_in,
                              void* d_out, int out_size, void* d_ws, size_t ws_size,
                              hipStream_t stream) {
    (void)in_sizes; (void)n_in; (void)out_size; (void)ws_size;
    const float* x_mm    = (const float*)d_in[0];
    const float* instf   = (const float*)d_in[1];
    const float* queries = (const float*)d_in[2];
    const float* W_proj  = (const float*)d_in[3];
    const float* b_proj  = (const float*)d_in[4];
    const float* W_kvi   = (const float*)d_in[5];
    const float* b_kvi   = (const float*)d_in[6];
    const float* W_oi    = (const float*)d_in[7];
    const float* b_oi    = (const float*)d_in[8];
    const float* W_kvm   = (const float*)d_in[9];
    const float* b_kvm   = (const float*)d_in[10];
    const float* W_om    = (const float*)d_in[11];
    const float* b_om    = (const float*)d_in[12];
    const float* ln_g    = (const float*)d_in[13];
    const float* ln_b    = (const float*)d_in[14];
    float* out = (float*)d_out;

    char* ws = (char*)d_ws;
    size_t off = 0;
    auto carve = [&](size_t bytes) -> char* {
        char* p = ws + off;
        off += (bytes + 255) & ~(size_t)255;
        return p;
    };
    unsigned short* x_bf   = (unsigned short*)carve((size_t)BATCH * MSEQ * MMHID * 2);
    unsigned short* wtm_bf = (unsigned short*)carve((size_t)2 * HIDDEN * MMHID * 2);
    unsigned short* kv_mm  = (unsigned short*)carve((size_t)BATCH * MSEQ * 2 * HIDDEN * 2);
    unsigned short* wp_bf  = (unsigned short*)carve((size_t)768 * 768 * 2);
    unsigned short* wkvi_bf= (unsigned short*)carve((size_t)1536 * 768 * 2);
    unsigned short* woi_bf = (unsigned short*)carve((size_t)768 * 768 * 2);
    unsigned short* wom_bf = (unsigned short*)carve((size_t)768 * 768 * 2);
    unsigned short* a1_bf  = (unsigned short*)carve((size_t)384 * 768 * 2);
    unsigned short* inst_bf= (unsigned short*)carve((size_t)384 * 768 * 2);
    float*          kv_inst= (float*)carve((size_t)384 * 1536 * 4);
    unsigned short* qatt_bf= (unsigned short*)carve((size_t)256 * 768 * 2);
    float*          q2     = (float*)carve((size_t)256 * 768 * 4);
    unsigned short* q2bf   = (unsigned short*)carve((size_t)BATCH * 128 * 768 * 2);
    float*          scores = (float*)carve((size_t)BATCH * 64 * MSEQ * 4);
    unsigned short* P_abs  = (unsigned short*)carve((size_t)BATCH * 64 * MSEQ * 2);
    float*          o_acc  = (float*)carve((size_t)BATCH * 64 * 768 * 4);
    unsigned short* a_bf   = (unsigned short*)carve((size_t)256 * 768 * 2);
    float2*         stats  = (float2*)carve((size_t)BATCH * MSEQ * 2 * sizeof(float2));
    float*          qgsum  = (float*)carve((size_t)256 * 4);
    float*          s2     = (float*)carve((size_t)256 * 4);

    // ---- prep: 5 weight transposes + instf cvt (z=5) + x cvt (z=6,7 grid-stride), single dispatch ----
    PrepJobs tw;
    tw.W[0] = W_kvm;  tw.Wt[0] = wtm_bf;  tw.D[0] = 1024; tw.C[0] = 1536;
    tw.W[1] = W_proj; tw.Wt[1] = wp_bf;   tw.D[1] = 768;  tw.C[1] = 768;
    tw.W[2] = W_kvi;  tw.Wt[2] = wkvi_bf; tw.D[2] = 768;  tw.C[2] = 1536;
    tw.W[3] = W_oi;   tw.Wt[3] = woi_bf;  tw.D[3] = 768;  tw.C[3] = 768;
    tw.W[4] = W_om;   tw.Wt[4] = wom_bf;  tw.D[4] = 768;  tw.C[4] = 768;
    tw.inst_in = instf; tw.inst_out = a1_bf;
    tw.n8_valid = BATCH * LI * 768 / 8; tw.n8_total = 384 * 768 / 8;
    tw.x_in = x_mm; tw.x_out = x_bf; tw.n8x = BATCH * MSEQ * MMHID / 8;
    prep_kernel<<<dim3(48, 32, 8), 256, 0, stream>>>(tw);

    // ---- mm branch: 256^2 double-buffered GEMM (R12-verified) -> vectorized stats ----
    hipError_t attr_ok = hipFuncSetAttribute((const void*)gemm_kv256_kernel,
                                             hipFuncAttributeMaxDynamicSharedMemorySize, 131072);
    if (attr_ok == hipSuccess) {
        gemm_kv256_kernel<<<(GM / 256) * (GN / 256), 512, 131072, stream>>>(x_bf, wtm_bf, b_kvm, kv_mm);
    } else {
        gemm_kv128_kernel<<<(GM / 128) * (GN / 128), 256, 0, stream>>>(x_bf, wtm_bf, b_kvm, kv_mm);
    }
    stats_kernel<<<2048, 256, 0, stream>>>(kv_mm, stats, BATCH * MSEQ * 2);

    // ---- inst branch (bf16 MFMA; LN of kv_inst folded into attn) ----
    gemm_tile_kernel<768, true><<<dim3(3, 6), 256, 0, stream>>>(a1_bf, wp_bf, b_proj, inst_bf, 768);
    gemm_tile_kernel<768, false><<<dim3(3, 12), 256, 0, stream>>>(inst_bf, wkvi_bf, b_kvi, kv_inst, 1536);
    attn_inst_kernel<<<BATCH * NQ, 256, 0, stream>>>(queries, kv_inst, ln_g, ln_b, qatt_bf);
    gemm_tile_kernel<768, false><<<dim3(2, 6), 256, 0, stream>>>(qatt_bf, woi_bf, b_oi, q2, 768);

    // ---- windowed attention ----
    cvt_q_kernel<<<BATCH * 128, 256, 0, stream>>>(q2, ln_g, ln_b, q2bf, qgsum);
    gemm_scores_kernel<<<dim3(MSEQ / 128, BATCH), 256, 0, stream>>>(q2bf, kv_mm, scores);
    win_softmax_kernel<<<BATCH * NQ, 512, 0, stream>>>(scores, stats, qgsum, P_abs, s2, o_acc);
    pv_chunk_kernel<<<dim3(MSEQ / 64, BATCH), 768, 0, stream>>>(P_abs, kv_mm, o_acc);
    out_affine_kernel<<<(BATCH * NQ * HIDDEN + 255) / 256, 256, 0, stream>>>(o_acc, s2, ln_g, ln_b, a_bf);

    // ---- output projection ----
    gemm_tile_kernel<768, false><<<dim3(2, 6), 256, 0, stream>>>(a_bf, wom_bf, b_om, out, 768);
    ln_f32_rows<<<BATCH * NQ, 256, 0, stream>>>(out, ln_g, ln_b);
}